// Round 2
// baseline (5488.008 us; speedup 1.0000x reference)
//
#include <hip/hip_runtime.h>

typedef _Float16 f16;
typedef _Float16 f16x8 __attribute__((ext_vector_type(8)));
typedef float    f32x4 __attribute__((ext_vector_type(4)));

#define MFMA16(a, b, c) __builtin_amdgcn_mfma_f32_16x16x32_f16((a), (b), (c), 0, 0, 0)

#define HSZ 262144            // 512*512
#define LOGDET_C 235.2482644923962f  // 128*log(2*pi)

// ---------------------------------------------------------------------------
// prep: base = [x*mask, mask] @ Wih0[:,1:257]^T + b_ih0 + b_hh0  (f32)
//       h0buf[0] = tanh(base) (= h0[t=0]); h1all[0] = 0 (= h1[t=-1])
//       convert weights to f16; zero cluster barrier counters.
__global__ void k_prep(const float* __restrict__ x, const float* __restrict__ mask,
                       const float* __restrict__ Wih0,
                       const float* __restrict__ b_ih0, const float* __restrict__ b_hh0,
                       const float* __restrict__ Whh0, const float* __restrict__ Wih1,
                       const float* __restrict__ Whh1, const float* __restrict__ W1,
                       const float* __restrict__ W2,
                       float* __restrict__ base, f16* __restrict__ Whh0h,
                       f16* __restrict__ Wih1h, f16* __restrict__ Whh1h,
                       f16* __restrict__ W1h, f16* __restrict__ W2h,
                       f16* __restrict__ h0buf, f16* __restrict__ h1all,
                       int* __restrict__ ctr)
{
    int gid = blockIdx.x * 256 + threadIdx.x;   // 0..65535
    for (int i = 0; i < 4; i++) {
        int idx = gid + 65536 * i;
        int r = idx >> 9, c = idx & 511;
        const float* wrow = Wih0 + c * 257;
        float s = b_ih0[c] + b_hh0[c];
        for (int k = 0; k < 128; k++) s += x[r * 128 + k] * mask[k] * wrow[1 + k];
        for (int k = 0; k < 128; k++) s += mask[k] * wrow[129 + k];
        base[idx] = s;
        h0buf[idx] = (f16)tanhf(s);           // h0[0]
    }
    for (int i = gid; i < 262144; i += 65536) {
        Whh0h[i] = (f16)Whh0[i];
        Wih1h[i] = (f16)Wih1[i];
        Whh1h[i] = (f16)Whh1[i];
    }
    for (int i = gid; i < 1048576; i += 65536) W1h[i] = (f16)W1[i];
    for (int i = gid; i < 524288;  i += 65536) W2h[i] = (f16)W2[i];
    for (int i = gid; i < HSZ; i += 65536) h1all[i] = (f16)0.f;  // h1[-1]
    if (gid < 16) ctr[gid] = 0;
}

// ---------------------------------------------------------------------------
// Persistent recurrence kernel. 256 wgs (16 clusters x 16 wgs), 1 wg/CU
// (forced by 96KB LDS). Cluster ci owns rows [32*ci, 32*ci+32); wg cj owns
// cols [32*cj, 32*cj+32) with Whh0/Wih1/Whh1 col-slices resident in LDS.
// Phase p (given h0[p], h1[p-1] complete for this cluster's rows):
//   h1[p]   = tanh(Wih1 @ h0[p] + Whh1 @ h1[p-1] + b)    -> h1all[p+1]
//   h0[p+1] = tanh(base + x[:,p] (x) w0col + Whh0 @ h0[p]) -> h0buf[(p+1)&1]
// then one cluster-local barrier (release/acquire at agent scope for
// cross-XCD visibility through L3).
__global__ __launch_bounds__(256, 1) void k_rnn(
    f16* __restrict__ h0buf, f16* __restrict__ h1all,
    const f16* __restrict__ Whh0h, const f16* __restrict__ Wih1h,
    const f16* __restrict__ Whh1h,
    const float* __restrict__ base, const float* __restrict__ x,
    const float* __restrict__ Wih0, const float* __restrict__ b_ih1,
    const float* __restrict__ b_hh1, int* __restrict__ ctr)
{
    __shared__ __align__(16) f16 Wl[3 * 32 * 512];   // 96 KB, XOR-swizzled
    int tid = threadIdx.x;
    int w = tid >> 6, l = tid & 63;
    int ci = blockIdx.x >> 4;        // cluster (row block)
    int cj = blockIdx.x & 15;        // col block
    int R0 = ci * 32, C0 = cj * 32;

    // ---- stage weight col-slices into LDS with bank-conflict swizzle
    {
        const f16* srcs[3] = { Whh0h, Wih1h, Whh1h };
        for (int m = 0; m < 3; m++) {
            const f16* S = srcs[m] + (size_t)C0 * 512;
            for (int cch = tid; cch < 2048; cch += 256) {   // 2048 x 16B chunks
                int col = cch >> 6, kc = cch & 63;
                f16x8 v = *(const f16x8*)(S + col * 512 + kc * 8);
                int byte = m * 32768 + col * 1024 + kc * 16;
                byte ^= (col & 7) << 4;
                *(f16x8*)((char*)Wl + byte) = v;
            }
        }
    }
    __syncthreads();

    int lr = l & 15, hi = l >> 4;
    int r_lo = (w >> 1) * 16, c_lo = (w & 1) * 16;
    int outrow = R0 + r_lo + hi * 4;        // +r for r in 0..3
    int outcolg = C0 + c_lo + lr;           // global output col
    int colL = c_lo + lr;                   // local col within wg slice

    float basef[4];
#pragma unroll
    for (int r = 0; r < 4; r++) basef[r] = base[(outrow + r) * 512 + outcolg];
    float w0 = Wih0[outcolg * 257];
    float bsum = b_ih1[outcolg] + b_hh1[outcolg];

#define LDB(m, k0) (*(const f16x8*)((char*)Wl + \
        ((((m) * 32768 + colL * 1024 + (k0) * 2)) ^ ((colL & 7) << 4))))

    for (int p = 0; p < 128; p++) {
        const f16* H0 = h0buf + (p & 1) * HSZ;
        const f16* H1 = h1all + (size_t)p * HSZ;

        f16x8 a0[16];
        const f16* ap = H0 + (R0 + r_lo + lr) * 512 + hi * 8;
#pragma unroll
        for (int f = 0; f < 16; f++) a0[f] = *(const f16x8*)(ap + f * 32);

        f32x4 acc1 = {0.f, 0.f, 0.f, 0.f}, acc0n = acc1;
#pragma unroll
        for (int f = 0; f < 16; f++) {
            acc1  = MFMA16(a0[f], LDB(1, f * 32 + hi * 8), acc1);
            acc0n = MFMA16(a0[f], LDB(0, f * 32 + hi * 8), acc0n);
        }
        f16x8 a1[16];
        const f16* bp = H1 + (R0 + r_lo + lr) * 512 + hi * 8;
#pragma unroll
        for (int f = 0; f < 16; f++) a1[f] = *(const f16x8*)(bp + f * 32);
#pragma unroll
        for (int f = 0; f < 16; f++)
            acc1 = MFMA16(a1[f], LDB(2, f * 32 + hi * 8), acc1);

        // epilogue
        f16* H1o = h1all + (size_t)(p + 1) * HSZ;
        f16* H0o = h0buf + ((p + 1) & 1) * HSZ;
        float xprev[4];
#pragma unroll
        for (int r = 0; r < 4; r++) xprev[r] = x[(outrow + r) * 128 + p];
#pragma unroll
        for (int r = 0; r < 4; r++) {
            H1o[(outrow + r) * 512 + outcolg] = (f16)tanhf(acc1[r] + bsum);
            H0o[(outrow + r) * 512 + outcolg] =
                (f16)tanhf(acc0n[r] + basef[r] + xprev[r] * w0);
        }

        if (p < 127) {
            __syncthreads();   // all wg stores retired (vmcnt(0) before s_barrier)
            if (tid == 0) {
                // release: flush this XCD's L2 so peers see our slice via L3
                __hip_atomic_fetch_add(ctr + ci, 1, __ATOMIC_RELEASE,
                                       __HIP_MEMORY_SCOPE_AGENT);
                int target = 16 * (p + 1);
                while (__hip_atomic_load(ctr + ci, __ATOMIC_RELAXED,
                                         __HIP_MEMORY_SCOPE_AGENT) < target)
                    __builtin_amdgcn_s_sleep(1);
                // acquire: invalidate L1/L2 so we re-fetch peers' fresh data
                __builtin_amdgcn_fence(__ATOMIC_ACQUIRE, "agent");
            }
            __syncthreads();
        }
    }
#undef LDB
}

// ---------------------------------------------------------------------------
// Phase B (fully parallel over (t, row-tile)):
//   hid = relu(h1_all[t+1] @ W1^T + b1); mc = hid @ W2^T + b2
//   pcontrib[t][row] = -0.5*(C + quad) - 0.5*sum(log(softplus(cov)))
__global__ __launch_bounds__(256) void k_phaseB(const f16* __restrict__ h1all,
                                                const f16* __restrict__ W1h,
                                                const f16* __restrict__ W2h,
                                                const float* __restrict__ b1,
                                                const float* __restrict__ b2,
                                                const float* __restrict__ x,
                                                float* __restrict__ pcontrib)
{
    __shared__ __align__(16) f16 hidlds[4][16][72];
    int tid = threadIdx.x;
    int w = tid >> 6, l = tid & 63;
    int t = blockIdx.x & 127, rtile = blockIdx.x >> 7;
    int R0 = rtile * 64 + w * 16;
    int lr = l & 15, hi = l >> 4, lk = hi * 8;
    const f16* H = h1all + (size_t)(t + 1) * HSZ;

    f32x4 mc[16] = {};
    for (int nc = 0; nc < 2048; nc += 64) {
        f32x4 acc3[4] = {};
        for (int kc = 0; kc < 16; kc++) {
            f16x8 a = *(const f16x8*)(H + (R0 + lr) * 512 + kc * 32 + lk);
#pragma unroll
            for (int ns = 0; ns < 4; ns++) {
                f16x8 b = *(const f16x8*)(W1h + (size_t)(nc + ns * 16 + lr) * 512 + kc * 32 + lk);
                acc3[ns] = MFMA16(a, b, acc3[ns]);
            }
        }
#pragma unroll
        for (int ns = 0; ns < 4; ns++) {
#pragma unroll
            for (int r = 0; r < 4; r++) {
                float v = acc3[ns][r] + b1[nc + ns * 16 + lr];
                hidlds[w][hi * 4 + r][ns * 16 + lr] = (f16)fmaxf(v, 0.f);
            }
        }
#pragma unroll
        for (int k4 = 0; k4 < 2; k4++) {
            f16x8 a4 = *(const f16x8*)(&hidlds[w][lr][k4 * 32 + lk]);
#pragma unroll
            for (int ms = 0; ms < 16; ms++) {
                f16x8 b = *(const f16x8*)(W2h + (size_t)(ms * 16 + lr) * 2048 + nc + k4 * 32 + lk);
                mc[ms] = MFMA16(a4, b, mc[ms]);
            }
        }
    }
    float quad[4] = {0.f, 0.f, 0.f, 0.f};
    float lsum[4] = {0.f, 0.f, 0.f, 0.f};
    float xt[4];
#pragma unroll
    for (int r = 0; r < 4; r++) xt[r] = x[(R0 + hi * 4 + r) * 128 + t];
#pragma unroll
    for (int ns = 0; ns < 8; ns++) {
        int c = ns * 16 + lr;
        float bm = b2[c], bc = b2[128 + c];
#pragma unroll
        for (int r = 0; r < 4; r++) {
            float mean = mc[ns][r] + bm;
            float cov  = mc[ns + 8][r] + bc;
            float sp = log1pf(expf(-fabsf(cov))) + fmaxf(cov, 0.f);  // softplus
            float d = xt[r] - mean;
            quad[r] += d * d * sp;
            lsum[r] += logf(sp);
        }
    }
#pragma unroll
    for (int m = 1; m < 16; m <<= 1) {
#pragma unroll
        for (int r = 0; r < 4; r++) {
            quad[r] += __shfl_xor(quad[r], m, 64);
            lsum[r] += __shfl_xor(lsum[r], m, 64);
        }
    }
    if (lr == 0) {
#pragma unroll
        for (int r = 0; r < 4; r++) {
            pcontrib[t * 512 + R0 + hi * 4 + r] =
                -0.5f * (LOGDET_C + quad[r]) - 0.5f * lsum[r];
        }
    }
}

// ---------------------------------------------------------------------------
__global__ void k_fin(const f16* __restrict__ h1last,
                      const float* __restrict__ pcontrib, float* __restrict__ out)
{
    int gid = blockIdx.x * 256 + threadIdx.x;
    for (int i = gid; i < HSZ; i += 131072) out[i] = (float)h1last[i];
    if (gid < 512) {
        float s = 0.f;
        for (int tt = 0; tt < 128; tt++) s += pcontrib[tt * 512 + gid];
        out[HSZ + gid] = s;
    }
}

// ---------------------------------------------------------------------------
extern "C" void kernel_launch(void* const* d_in, const int* in_sizes, int n_in,
                              void* d_out, int out_size, void* d_ws, size_t ws_size,
                              hipStream_t stream) {
    const float* x     = (const float*)d_in[0];
    const float* mask  = (const float*)d_in[1];
    const float* Wih0  = (const float*)d_in[2];
    const float* Whh0  = (const float*)d_in[3];
    const float* b_ih0 = (const float*)d_in[4];
    const float* b_hh0 = (const float*)d_in[5];
    const float* Wih1  = (const float*)d_in[6];
    const float* Whh1  = (const float*)d_in[7];
    const float* b_ih1 = (const float*)d_in[8];
    const float* b_hh1 = (const float*)d_in[9];
    const float* W1    = (const float*)d_in[10];
    const float* b1    = (const float*)d_in[11];
    const float* W2    = (const float*)d_in[12];
    const float* b2    = (const float*)d_in[13];

    char* ws = (char*)d_ws;
    size_t off = 0;
    auto take = [&](size_t bytes) { char* p = ws + off; off += (bytes + 255) & ~(size_t)255; return p; };
    float* base    = (float*)take(512 * 512 * 4);
    f16* Whh0h     = (f16*)take(HSZ * 2);
    f16* Wih1h     = (f16*)take(HSZ * 2);
    f16* Whh1h     = (f16*)take(HSZ * 2);
    f16* W1h       = (f16*)take(1048576 * 2);
    f16* W2h       = (f16*)take(524288 * 2);
    f16* h0buf     = (f16*)take(2 * HSZ * 2);
    f16* h1all     = (f16*)take((size_t)129 * HSZ * 2);
    float* pcontrib= (float*)take(128 * 512 * 4);
    int* ctr       = (int*)take(16 * 4);
    if (off > ws_size) return;

    k_prep<<<256, 256, 0, stream>>>(x, mask, Wih0, b_ih0, b_hh0, Whh0, Wih1, Whh1,
                                    W1, W2, base, Whh0h, Wih1h, Whh1h, W1h, W2h,
                                    h0buf, h1all, ctr);
    k_rnn<<<256, 256, 0, stream>>>(h0buf, h1all, Whh0h, Wih1h, Whh1h,
                                   base, x, Wih0, b_ih1, b_hh1, ctr);
    k_phaseB<<<1024, 256, 0, stream>>>(h1all, W1h, W2h, b1, b2, x, pcontrib);
    k_fin<<<512, 256, 0, stream>>>(h1all + (size_t)128 * HSZ, pcontrib, (float*)d_out);
}

// Round 3
// 3613.705 us; speedup vs baseline: 1.5187x; 1.5187x over previous
//
#include <hip/hip_runtime.h>

typedef _Float16 f16;
typedef _Float16 f16x8 __attribute__((ext_vector_type(8)));
typedef float    f32x4 __attribute__((ext_vector_type(4)));
typedef unsigned int u32;
typedef u32 u32x4 __attribute__((ext_vector_type(4)));

#define MFMA16(a, b, c) __builtin_amdgcn_mfma_f32_16x16x32_f16((a), (b), (c), 0, 0, 0)

#define HSZ 262144            // 512*512
#define LOGDET_C 235.2482644923962f  // 128*log(2*pi)

// Coherent (cross-XCD) 16B load: bypasses L1/L2, reads at L3 coherence point.
__device__ __forceinline__ void ld16(u32x4& d, const f16* p) {
    asm volatile("global_load_dwordx4 %0, %1, off sc0 sc1" : "=v"(d) : "v"(p));
}
// Coherent 2B store: write-through to L3 coherence point.
__device__ __forceinline__ void st2(f16* p, f16 v) {
    u32 u = (u32)__builtin_bit_cast(unsigned short, v);
    asm volatile("global_store_short %0, %1, off sc0 sc1" :: "v"(p), "v"(u) : "memory");
}

// ---------------------------------------------------------------------------
// k_conv: cheap conversions + small vectors.
//   A[r][k]  = x[r][k]*mask[k]            (f16, 512x128)
//   B1[c][k] = Wih0[c][1+k]               (f16, 512x128)
//   biasv[c] = b_ih0[c]+b_hh0[c]+sum_k mask[k]*Wih0[c][129+k]
//   weight f16 conversions; h1all[0]=0; slots=0.
__global__ void k_conv(const float* __restrict__ x, const float* __restrict__ mask,
                       const float* __restrict__ Wih0,
                       const float* __restrict__ b_ih0, const float* __restrict__ b_hh0,
                       const float* __restrict__ Whh0, const float* __restrict__ Wih1,
                       const float* __restrict__ Whh1, const float* __restrict__ W1,
                       const float* __restrict__ W2,
                       f16* __restrict__ A, f16* __restrict__ B1,
                       float* __restrict__ biasv,
                       f16* __restrict__ Whh0h, f16* __restrict__ Wih1h,
                       f16* __restrict__ Whh1h, f16* __restrict__ W1h,
                       f16* __restrict__ W2h, f16* __restrict__ h1all,
                       int* __restrict__ slots)
{
    int gid = blockIdx.x * 256 + threadIdx.x;   // 0..65535
    {
        int c = gid >> 7, k = gid & 127;
        A[gid]  = (f16)(x[gid] * mask[k]);
        B1[gid] = (f16)Wih0[c * 257 + 1 + k];
    }
    if (gid < 512) {
        float s = b_ih0[gid] + b_hh0[gid];
        const float* wrow = Wih0 + gid * 257 + 129;
        for (int k = 0; k < 128; k++) s += mask[k] * wrow[k];
        biasv[gid] = s;
    }
    for (int i = gid; i < 262144; i += 65536) {
        Whh0h[i] = (f16)Whh0[i];
        Wih1h[i] = (f16)Wih1[i];
        Whh1h[i] = (f16)Whh1[i];
        h1all[i] = (f16)0.f;      // h1[t=-1]
    }
    for (int i = gid; i < 1048576; i += 65536) W1h[i] = (f16)W1[i];
    for (int i = gid; i < 524288;  i += 65536) W2h[i] = (f16)W2[i];
    if (gid < 4096) slots[gid] = 0;
}

// ---------------------------------------------------------------------------
// k_base: base = A @ B1^T + biasv (512x512x128 MFMA GEMM, f32 out)
//         h0buf[0] = tanh(base)
// 256 wgs, 32x32 tile, 4 waves K-split (32 each), LDS reduce.
__global__ __launch_bounds__(256) void k_base(const f16* __restrict__ A,
                                              const f16* __restrict__ B1,
                                              const float* __restrict__ biasv,
                                              float* __restrict__ base,
                                              f16* __restrict__ h0buf)
{
    __shared__ float part[4][32][32];
    int tid = threadIdx.x;
    int w = tid >> 6, l = tid & 63;
    int R0 = (blockIdx.x >> 4) * 32, C0 = (blockIdx.x & 15) * 32;
    int lr = l & 15, hi = l >> 4;

    const f16* a0p = A  + (R0 + lr) * 128 + w * 32 + hi * 8;
    const f16* b0p = B1 + (C0 + lr) * 128 + w * 32 + hi * 8;
    f16x8 a0 = *(const f16x8*)(a0p);
    f16x8 a1 = *(const f16x8*)(a0p + 16 * 128);
    f16x8 b0 = *(const f16x8*)(b0p);
    f16x8 b1 = *(const f16x8*)(b0p + 16 * 128);
    f32x4 z = {0.f, 0.f, 0.f, 0.f};
    f32x4 acc00 = MFMA16(a0, b0, z);
    f32x4 acc01 = MFMA16(a0, b1, z);
    f32x4 acc10 = MFMA16(a1, b0, z);
    f32x4 acc11 = MFMA16(a1, b1, z);
#pragma unroll
    for (int r = 0; r < 4; r++) {
        part[w][hi * 4 + r][lr]           = acc00[r];
        part[w][hi * 4 + r][16 + lr]      = acc01[r];
        part[w][16 + hi * 4 + r][lr]      = acc10[r];
        part[w][16 + hi * 4 + r][16 + lr] = acc11[r];
    }
    __syncthreads();
    int rr = tid >> 3, c0 = (tid & 7) * 4;
    int gr = R0 + rr;
#pragma unroll
    for (int cc = 0; cc < 4; cc++) {
        int gc = C0 + c0 + cc;
        float s = part[0][rr][c0 + cc] + part[1][rr][c0 + cc] +
                  part[2][rr][c0 + cc] + part[3][rr][c0 + cc] + biasv[gc];
        base[gr * 512 + gc] = s;
        h0buf[gr * 512 + gc] = (f16)tanhf(s);
    }
}

// ---------------------------------------------------------------------------
// Persistent recurrence kernel. 256 wgs (16 clusters x 16 wgs), 1 wg/CU
// (forced by 96KB LDS -> guaranteed co-residency, as verified in round 2).
// Cross-XCD message passing is fence-free: data moves via sc0|sc1
// (write-through / L3-coherent) accesses; the per-phase cluster barrier is
// one padded per-wg slot (single writer per cacheline, relaxed agent scope)
// polled by 16 lanes of wave 0. No wbl2/inv anywhere.
__global__ __launch_bounds__(256, 1) void k_rnn(
    f16* __restrict__ h0buf, f16* __restrict__ h1all,
    const f16* __restrict__ Whh0h, const f16* __restrict__ Wih1h,
    const f16* __restrict__ Whh1h,
    const float* __restrict__ base, const float* __restrict__ x,
    const float* __restrict__ Wih0, const float* __restrict__ b_ih1,
    const float* __restrict__ b_hh1, int* __restrict__ slots)
{
    __shared__ __align__(16) f16 Wl[3 * 32 * 512];   // 96 KB, XOR-swizzled
    int tid = threadIdx.x;
    int w = tid >> 6, l = tid & 63;
    int ci = blockIdx.x >> 4;        // cluster (row block)
    int cj = blockIdx.x & 15;        // col block
    int R0 = ci * 32, C0 = cj * 32;

    // ---- stage weight col-slices into LDS with bank-conflict swizzle
    {
        const f16* srcs[3] = { Whh0h, Wih1h, Whh1h };
        for (int m = 0; m < 3; m++) {
            const f16* S = srcs[m] + (size_t)C0 * 512;
            for (int cch = tid; cch < 2048; cch += 256) {
                int col = cch >> 6, kc = cch & 63;
                f16x8 v = *(const f16x8*)(S + col * 512 + kc * 8);
                int byte = m * 32768 + col * 1024 + kc * 16;
                byte ^= (col & 7) << 4;
                *(f16x8*)((char*)Wl + byte) = v;
            }
        }
    }
    __syncthreads();

    int lr = l & 15, hi = l >> 4;
    int r_lo = (w >> 1) * 16, c_lo = (w & 1) * 16;
    int outrow = R0 + r_lo + hi * 4;        // +r for r in 0..3
    int outcolg = C0 + c_lo + lr;           // global output col
    int colL = c_lo + lr;                   // local col within wg slice

    float basef[4];
#pragma unroll
    for (int r = 0; r < 4; r++) basef[r] = base[(outrow + r) * 512 + outcolg];
    float w0 = Wih0[outcolg * 257];
    float bsum = b_ih1[outcolg] + b_hh1[outcolg];

    int* myslot = slots + (ci * 16 + cj) * 16;          // 64B-padded slot
    int* peerslot = slots + (ci * 16 + (l & 15)) * 16;  // lanes 0..15 poll

#define LDB(m, k0) (*(const f16x8*)((char*)Wl + \
        ((((m) * 32768 + colL * 1024 + (k0) * 2)) ^ ((colL & 7) << 4))))

    for (int p = 0; p < 128; p++) {
        const f16* H0 = h0buf + (p & 1) * HSZ;
        const f16* H1 = h1all + (size_t)p * HSZ;
        const f16* ap = H0 + (R0 + r_lo + lr) * 512 + hi * 8;
        const f16* bp = H1 + (R0 + r_lo + lr) * 512 + hi * 8;

        float xprev[4];
#pragma unroll
        for (int r = 0; r < 4; r++) xprev[r] = x[(outrow + r) * 128 + p];

        u32x4 ra0[16], ra1[16];
        __builtin_amdgcn_sched_barrier(0);
#pragma unroll
        for (int f = 0; f < 16; f++) ld16(ra0[f], ap + f * 32);
#pragma unroll
        for (int f = 0; f < 16; f++) ld16(ra1[f], bp + f * 32);
        asm volatile("s_waitcnt vmcnt(0)" ::: "memory");
        __builtin_amdgcn_sched_barrier(0);

        f32x4 acc1 = {0.f, 0.f, 0.f, 0.f}, acc0n = acc1;
#pragma unroll
        for (int f = 0; f < 16; f++) {
            f16x8 a = __builtin_bit_cast(f16x8, ra0[f]);
            acc1  = MFMA16(a, LDB(1, f * 32 + hi * 8), acc1);
            acc0n = MFMA16(a, LDB(0, f * 32 + hi * 8), acc0n);
        }
#pragma unroll
        for (int f = 0; f < 16; f++) {
            f16x8 a = __builtin_bit_cast(f16x8, ra1[f]);
            acc1 = MFMA16(a, LDB(2, f * 32 + hi * 8), acc1);
        }

        f16* H1o = h1all + (size_t)(p + 1) * HSZ;
        f16* H0o = h0buf + ((p + 1) & 1) * HSZ;
#pragma unroll
        for (int r = 0; r < 4; r++) {
            f16 v1 = (f16)tanhf(acc1[r] + bsum);
            f16 v0 = (f16)tanhf(acc0n[r] + basef[r] + xprev[r] * w0);
            st2(H1o + (outrow + r) * 512 + outcolg, v1);
            st2(H0o + (outrow + r) * 512 + outcolg, v0);
        }

        if (p < 127) {
            // drain own write-through stores, then cluster barrier
            asm volatile("s_waitcnt vmcnt(0)" ::: "memory");
            __syncthreads();
            if (w == 0) {
                int target = p + 1;
                if (l == 0)
                    __hip_atomic_store(myslot, target, __ATOMIC_RELAXED,
                                       __HIP_MEMORY_SCOPE_AGENT);
                int ok;
                do {
                    int v = 0x7fffffff;
                    if (l < 16)
                        v = __hip_atomic_load(peerslot, __ATOMIC_RELAXED,
                                              __HIP_MEMORY_SCOPE_AGENT);
                    ok = __all(v >= target);
                } while (!ok);
            }
            __syncthreads();
        }
    }
#undef LDB
}

// ---------------------------------------------------------------------------
// Phase B (fully parallel over (t, row-tile)):
//   hid = relu(h1_all[t+1] @ W1^T + b1); mc = hid @ W2^T + b2
//   pcontrib[t][row] = -0.5*(C + quad) - 0.5*sum(log(softplus(cov)))
__global__ __launch_bounds__(256) void k_phaseB(const f16* __restrict__ h1all,
                                                const f16* __restrict__ W1h,
                                                const f16* __restrict__ W2h,
                                                const float* __restrict__ b1,
                                                const float* __restrict__ b2,
                                                const float* __restrict__ x,
                                                float* __restrict__ pcontrib)
{
    __shared__ __align__(16) f16 hidlds[4][16][72];
    int tid = threadIdx.x;
    int w = tid >> 6, l = tid & 63;
    int t = blockIdx.x & 127, rtile = blockIdx.x >> 7;
    int R0 = rtile * 64 + w * 16;
    int lr = l & 15, hi = l >> 4, lk = hi * 8;
    const f16* H = h1all + (size_t)(t + 1) * HSZ;

    f32x4 mc[16] = {};
    for (int nc = 0; nc < 2048; nc += 64) {
        f32x4 acc3[4] = {};
        for (int kc = 0; kc < 16; kc++) {
            f16x8 a = *(const f16x8*)(H + (R0 + lr) * 512 + kc * 32 + lk);
#pragma unroll
            for (int ns = 0; ns < 4; ns++) {
                f16x8 b = *(const f16x8*)(W1h + (size_t)(nc + ns * 16 + lr) * 512 + kc * 32 + lk);
                acc3[ns] = MFMA16(a, b, acc3[ns]);
            }
        }
#pragma unroll
        for (int ns = 0; ns < 4; ns++) {
#pragma unroll
            for (int r = 0; r < 4; r++) {
                float v = acc3[ns][r] + b1[nc + ns * 16 + lr];
                hidlds[w][hi * 4 + r][ns * 16 + lr] = (f16)fmaxf(v, 0.f);
            }
        }
#pragma unroll
        for (int k4 = 0; k4 < 2; k4++) {
            f16x8 a4 = *(const f16x8*)(&hidlds[w][lr][k4 * 32 + lk]);
#pragma unroll
            for (int ms = 0; ms < 16; ms++) {
                f16x8 b = *(const f16x8*)(W2h + (size_t)(ms * 16 + lr) * 2048 + nc + k4 * 32 + lk);
                mc[ms] = MFMA16(a4, b, mc[ms]);
            }
        }
    }
    float quad[4] = {0.f, 0.f, 0.f, 0.f};
    float lsum[4] = {0.f, 0.f, 0.f, 0.f};
    float xt[4];
#pragma unroll
    for (int r = 0; r < 4; r++) xt[r] = x[(R0 + hi * 4 + r) * 128 + t];
#pragma unroll
    for (int ns = 0; ns < 8; ns++) {
        int c = ns * 16 + lr;
        float bm = b2[c], bc = b2[128 + c];
#pragma unroll
        for (int r = 0; r < 4; r++) {
            float mean = mc[ns][r] + bm;
            float cov  = mc[ns + 8][r] + bc;
            float sp = log1pf(expf(-fabsf(cov))) + fmaxf(cov, 0.f);  // softplus
            float d = xt[r] - mean;
            quad[r] += d * d * sp;
            lsum[r] += logf(sp);
        }
    }
#pragma unroll
    for (int m = 1; m < 16; m <<= 1) {
#pragma unroll
        for (int r = 0; r < 4; r++) {
            quad[r] += __shfl_xor(quad[r], m, 64);
            lsum[r] += __shfl_xor(lsum[r], m, 64);
        }
    }
    if (lr == 0) {
#pragma unroll
        for (int r = 0; r < 4; r++) {
            pcontrib[t * 512 + R0 + hi * 4 + r] =
                -0.5f * (LOGDET_C + quad[r]) - 0.5f * lsum[r];
        }
    }
}

// ---------------------------------------------------------------------------
__global__ void k_fin(const f16* __restrict__ h1last,
                      const float* __restrict__ pcontrib, float* __restrict__ out)
{
    int gid = blockIdx.x * 256 + threadIdx.x;
    for (int i = gid; i < HSZ; i += 131072) out[i] = (float)h1last[i];
    if (gid < 512) {
        float s = 0.f;
        for (int tt = 0; tt < 128; tt++) s += pcontrib[tt * 512 + gid];
        out[HSZ + gid] = s;
    }
}

// ---------------------------------------------------------------------------
extern "C" void kernel_launch(void* const* d_in, const int* in_sizes, int n_in,
                              void* d_out, int out_size, void* d_ws, size_t ws_size,
                              hipStream_t stream) {
    const float* x     = (const float*)d_in[0];
    const float* mask  = (const float*)d_in[1];
    const float* Wih0  = (const float*)d_in[2];
    const float* Whh0  = (const float*)d_in[3];
    const float* b_ih0 = (const float*)d_in[4];
    const float* b_hh0 = (const float*)d_in[5];
    const float* Wih1  = (const float*)d_in[6];
    const float* Whh1  = (const float*)d_in[7];
    const float* b_ih1 = (const float*)d_in[8];
    const float* b_hh1 = (const float*)d_in[9];
    const float* W1    = (const float*)d_in[10];
    const float* b1    = (const float*)d_in[11];
    const float* W2    = (const float*)d_in[12];
    const float* b2    = (const float*)d_in[13];

    char* ws = (char*)d_ws;
    size_t off = 0;
    auto take = [&](size_t bytes) { char* p = ws + off; off += (bytes + 255) & ~(size_t)255; return p; };
    float* base    = (float*)take(512 * 512 * 4);
    f16* Whh0h     = (f16*)take(HSZ * 2);
    f16* Wih1h     = (f16*)take(HSZ * 2);
    f16* Whh1h     = (f16*)take(HSZ * 2);
    f16* W1h       = (f16*)take(1048576 * 2);
    f16* W2h       = (f16*)take(524288 * 2);
    f16* h0buf     = (f16*)take(2 * HSZ * 2);
    f16* h1all     = (f16*)take((size_t)129 * HSZ * 2);
    float* pcontrib= (float*)take(128 * 512 * 4);
    f16* A         = (f16*)take(65536 * 2);
    f16* B1        = (f16*)take(65536 * 2);
    float* biasv   = (float*)take(512 * 4);
    int* slots     = (int*)take(4096 * 4);
    if (off > ws_size) return;

    k_conv<<<256, 256, 0, stream>>>(x, mask, Wih0, b_ih0, b_hh0, Whh0, Wih1, Whh1,
                                    W1, W2, A, B1, biasv, Whh0h, Wih1h, Whh1h,
                                    W1h, W2h, h1all, slots);
    k_base<<<256, 256, 0, stream>>>(A, B1, biasv, base, h0buf);
    k_rnn<<<256, 256, 0, stream>>>(h0buf, h1all, Whh0h, Wih1h, Whh1h,
                                   base, x, Wih0, b_ih1, b_hh1, slots);
    k_phaseB<<<1024, 256, 0, stream>>>(h1all, W1h, W2h, b1, b2, x, pcontrib);
    k_fin<<<512, 256, 0, stream>>>(h1all + (size_t)128 * HSZ, pcontrib, (float*)d_out);
}

// Round 4
// 2030.113 us; speedup vs baseline: 2.7033x; 1.7801x over previous
//
#include <hip/hip_runtime.h>

typedef _Float16 f16;
typedef _Float16 f16x8 __attribute__((ext_vector_type(8)));
typedef float    f32x4 __attribute__((ext_vector_type(4)));
typedef unsigned int u32;
typedef u32 u32x4 __attribute__((ext_vector_type(4)));

#define MFMA16(a, b, c) __builtin_amdgcn_mfma_f32_16x16x32_f16((a), (b), (c), 0, 0, 0)

#define HSZ 262144            // 512*512
#define LOGDET_C 235.2482644923962f  // 128*log(2*pi)

// Coherent (cross-XCD) 16B load: reads at L3 coherence point.
__device__ __forceinline__ void ld16(u32x4& d, const f16* p) {
    asm volatile("global_load_dwordx4 %0, %1, off sc0 sc1" : "=v"(d) : "v"(p));
}
// Coherent 2B store: write-through to L3 coherence point.
__device__ __forceinline__ void st2(f16* p, f16 v) {
    u32 u = (u32)__builtin_bit_cast(unsigned short, v);
    asm volatile("global_store_short %0, %1, off sc0 sc1" :: "v"(p), "v"(u) : "memory");
}
// async global->LDS 16B (per-lane global src, wave-linear LDS dest)
__device__ __forceinline__ void gl16(const f16* g, char* l) {
    __builtin_amdgcn_global_load_lds(
        (const __attribute__((address_space(1))) u32*)g,
        (__attribute__((address_space(3))) u32*)l, 16, 0, 0);
}

// ---------------------------------------------------------------------------
// k_conv: conversions + small vectors (unchanged from round 3)
__global__ void k_conv(const float* __restrict__ x, const float* __restrict__ mask,
                       const float* __restrict__ Wih0,
                       const float* __restrict__ b_ih0, const float* __restrict__ b_hh0,
                       const float* __restrict__ Whh0, const float* __restrict__ Wih1,
                       const float* __restrict__ Whh1, const float* __restrict__ W1,
                       const float* __restrict__ W2,
                       f16* __restrict__ A, f16* __restrict__ B1,
                       float* __restrict__ biasv,
                       f16* __restrict__ Whh0h, f16* __restrict__ Wih1h,
                       f16* __restrict__ Whh1h, f16* __restrict__ W1h,
                       f16* __restrict__ W2h, f16* __restrict__ h1all,
                       int* __restrict__ slots)
{
    int gid = blockIdx.x * 256 + threadIdx.x;   // 0..65535
    {
        int c = gid >> 7, k = gid & 127;
        A[gid]  = (f16)(x[gid] * mask[k]);
        B1[gid] = (f16)Wih0[c * 257 + 1 + k];
    }
    if (gid < 512) {
        float s = b_ih0[gid] + b_hh0[gid];
        const float* wrow = Wih0 + gid * 257 + 129;
        for (int k = 0; k < 128; k++) s += mask[k] * wrow[k];
        biasv[gid] = s;
    }
    for (int i = gid; i < 262144; i += 65536) {
        Whh0h[i] = (f16)Whh0[i];
        Wih1h[i] = (f16)Wih1[i];
        Whh1h[i] = (f16)Whh1[i];
        h1all[i] = (f16)0.f;      // h1[t=-1]
    }
    for (int i = gid; i < 1048576; i += 65536) W1h[i] = (f16)W1[i];
    for (int i = gid; i < 524288;  i += 65536) W2h[i] = (f16)W2[i];
    if (gid < 4096) slots[gid] = 0;
}

// ---------------------------------------------------------------------------
// k_base: base = A @ B1^T + biasv ; h0buf[0] = tanh(base)  (unchanged)
__global__ __launch_bounds__(256) void k_base(const f16* __restrict__ A,
                                              const f16* __restrict__ B1,
                                              const float* __restrict__ biasv,
                                              float* __restrict__ base,
                                              f16* __restrict__ h0buf)
{
    __shared__ float part[4][32][32];
    int tid = threadIdx.x;
    int w = tid >> 6, l = tid & 63;
    int R0 = (blockIdx.x >> 4) * 32, C0 = (blockIdx.x & 15) * 32;
    int lr = l & 15, hi = l >> 4;

    const f16* a0p = A  + (R0 + lr) * 128 + w * 32 + hi * 8;
    const f16* b0p = B1 + (C0 + lr) * 128 + w * 32 + hi * 8;
    f16x8 a0 = *(const f16x8*)(a0p);
    f16x8 a1 = *(const f16x8*)(a0p + 16 * 128);
    f16x8 b0 = *(const f16x8*)(b0p);
    f16x8 b1 = *(const f16x8*)(b0p + 16 * 128);
    f32x4 z = {0.f, 0.f, 0.f, 0.f};
    f32x4 acc00 = MFMA16(a0, b0, z);
    f32x4 acc01 = MFMA16(a0, b1, z);
    f32x4 acc10 = MFMA16(a1, b0, z);
    f32x4 acc11 = MFMA16(a1, b1, z);
#pragma unroll
    for (int r = 0; r < 4; r++) {
        part[w][hi * 4 + r][lr]           = acc00[r];
        part[w][hi * 4 + r][16 + lr]      = acc01[r];
        part[w][16 + hi * 4 + r][lr]      = acc10[r];
        part[w][16 + hi * 4 + r][16 + lr] = acc11[r];
    }
    __syncthreads();
    int rr = tid >> 3, c0 = (tid & 7) * 4;
    int gr = R0 + rr;
#pragma unroll
    for (int cc = 0; cc < 4; cc++) {
        int gc = C0 + c0 + cc;
        float s = part[0][rr][c0 + cc] + part[1][rr][c0 + cc] +
                  part[2][rr][c0 + cc] + part[3][rr][c0 + cc] + biasv[gc];
        base[gr * 512 + gc] = s;
        h0buf[gr * 512 + gc] = (f16)tanhf(s);
    }
}

// ---------------------------------------------------------------------------
// Persistent recurrence kernel (unchanged from round 3).
__global__ __launch_bounds__(256, 1) void k_rnn(
    f16* __restrict__ h0buf, f16* __restrict__ h1all,
    const f16* __restrict__ Whh0h, const f16* __restrict__ Wih1h,
    const f16* __restrict__ Whh1h,
    const float* __restrict__ base, const float* __restrict__ x,
    const float* __restrict__ Wih0, const float* __restrict__ b_ih1,
    const float* __restrict__ b_hh1, int* __restrict__ slots)
{
    __shared__ __align__(16) f16 Wl[3 * 32 * 512];   // 96 KB, XOR-swizzled
    int tid = threadIdx.x;
    int w = tid >> 6, l = tid & 63;
    int ci = blockIdx.x >> 4;        // cluster (row block)
    int cj = blockIdx.x & 15;        // col block
    int R0 = ci * 32, C0 = cj * 32;

    {
        const f16* srcs[3] = { Whh0h, Wih1h, Whh1h };
        for (int m = 0; m < 3; m++) {
            const f16* S = srcs[m] + (size_t)C0 * 512;
            for (int cch = tid; cch < 2048; cch += 256) {
                int col = cch >> 6, kc = cch & 63;
                f16x8 v = *(const f16x8*)(S + col * 512 + kc * 8);
                int byte = m * 32768 + col * 1024 + kc * 16;
                byte ^= (col & 7) << 4;
                *(f16x8*)((char*)Wl + byte) = v;
            }
        }
    }
    __syncthreads();

    int lr = l & 15, hi = l >> 4;
    int r_lo = (w >> 1) * 16, c_lo = (w & 1) * 16;
    int outrow = R0 + r_lo + hi * 4;
    int outcolg = C0 + c_lo + lr;
    int colL = c_lo + lr;

    float basef[4];
#pragma unroll
    for (int r = 0; r < 4; r++) basef[r] = base[(outrow + r) * 512 + outcolg];
    float w0 = Wih0[outcolg * 257];
    float bsum = b_ih1[outcolg] + b_hh1[outcolg];

    int* myslot = slots + (ci * 16 + cj) * 16;
    int* peerslot = slots + (ci * 16 + (l & 15)) * 16;

#define LDB(m, k0) (*(const f16x8*)((char*)Wl + \
        ((((m) * 32768 + colL * 1024 + (k0) * 2)) ^ ((colL & 7) << 4))))

    for (int p = 0; p < 128; p++) {
        const f16* H0 = h0buf + (p & 1) * HSZ;
        const f16* H1 = h1all + (size_t)p * HSZ;
        const f16* ap = H0 + (R0 + r_lo + lr) * 512 + hi * 8;
        const f16* bp = H1 + (R0 + r_lo + lr) * 512 + hi * 8;

        float xprev[4];
#pragma unroll
        for (int r = 0; r < 4; r++) xprev[r] = x[(outrow + r) * 128 + p];

        u32x4 ra0[16], ra1[16];
        __builtin_amdgcn_sched_barrier(0);
#pragma unroll
        for (int f = 0; f < 16; f++) ld16(ra0[f], ap + f * 32);
#pragma unroll
        for (int f = 0; f < 16; f++) ld16(ra1[f], bp + f * 32);
        asm volatile("s_waitcnt vmcnt(0)" ::: "memory");
        __builtin_amdgcn_sched_barrier(0);

        f32x4 acc1 = {0.f, 0.f, 0.f, 0.f}, acc0n = acc1;
#pragma unroll
        for (int f = 0; f < 16; f++) {
            f16x8 a = __builtin_bit_cast(f16x8, ra0[f]);
            acc1  = MFMA16(a, LDB(1, f * 32 + hi * 8), acc1);
            acc0n = MFMA16(a, LDB(0, f * 32 + hi * 8), acc0n);
        }
#pragma unroll
        for (int f = 0; f < 16; f++) {
            f16x8 a = __builtin_bit_cast(f16x8, ra1[f]);
            acc1 = MFMA16(a, LDB(2, f * 32 + hi * 8), acc1);
        }

        f16* H1o = h1all + (size_t)(p + 1) * HSZ;
        f16* H0o = h0buf + ((p + 1) & 1) * HSZ;
#pragma unroll
        for (int r = 0; r < 4; r++) {
            f16 v1 = (f16)tanhf(acc1[r] + bsum);
            f16 v0 = (f16)tanhf(acc0n[r] + basef[r] + xprev[r] * w0);
            st2(H1o + (outrow + r) * 512 + outcolg, v1);
            st2(H0o + (outrow + r) * 512 + outcolg, v0);
        }

        if (p < 127) {
            asm volatile("s_waitcnt vmcnt(0)" ::: "memory");
            __syncthreads();
            if (w == 0) {
                int target = p + 1;
                if (l == 0)
                    __hip_atomic_store(myslot, target, __ATOMIC_RELAXED,
                                       __HIP_MEMORY_SCOPE_AGENT);
                int ok;
                do {
                    int v = 0x7fffffff;
                    if (l < 16)
                        v = __hip_atomic_load(peerslot, __ATOMIC_RELAXED,
                                              __HIP_MEMORY_SCOPE_AGENT);
                    ok = __all(v >= target);
                } while (!ok);
            }
            __syncthreads();
        }
    }
#undef LDB
}

// ---------------------------------------------------------------------------
// Phase B v2: one GEMM-shaped fused kernel over flattened m = t*512+row.
// grid 256 wgs x 512 thr (8 waves). wg M-tile = 256 rows; wave = 32 rows x
// all 256 mc cols (acc 128 VGPR). NC chunk = 32, W1/W2 chunks double-buffered
// in LDS via global_load_lds; hid scratch in LDS. Layouts are
// [k-group][col][8 halves] so all MFMA-fragment ds_reads are 16B-stride
// (2-way bank = free). 2 barriers per chunk; staging overlaps compute.
// LDS: W1c 2x32KB + W2c 2x16KB + hid 16KB = 112 KB -> 1 wg/CU, 2 waves/SIMD.
__global__ __launch_bounds__(512, 2) void k_phaseB(const f16* __restrict__ h1all,
                                                   const f16* __restrict__ W1h,
                                                   const f16* __restrict__ W2h,
                                                   const float* __restrict__ b1v,
                                                   const float* __restrict__ b2,
                                                   const float* __restrict__ x,
                                                   float* __restrict__ pcontrib)
{
    __shared__ __align__(16) char Wl[114688];
    const int OFF_W2 = 65536, OFF_HID = 98304;

    int tid = threadIdx.x;
    int wv = tid >> 6, l = tid & 63;
    int lr = l & 15, hi = l >> 4;
    int M0 = blockIdx.x * 256;

    const f16* Hbase = h1all + HSZ + (size_t)(M0 + wv * 32 + lr) * 512;

    f32x4 mc[2][16] = {};

    // prologue: stage chunk 0 into buf 0
    {
        const int nc = 0, p = 0;
#pragma unroll
        for (int it = 0; it < 4; it++) {
            int blk = it * 8 + wv;            // 0..31
            int idx = blk * 64 + l;           // 0..2047
            int col = idx & 31, kh = idx >> 5;
            gl16(W1h + (size_t)(nc + col) * 512 + kh * 8,
                 Wl + p * 32768 + blk * 1024);
        }
#pragma unroll
        for (int it = 0; it < 2; it++) {
            int blk = it * 8 + wv;            // 0..15
            int idx = blk * 64 + l;
            int col = idx & 255, khi = idx >> 8;
            gl16(W2h + (size_t)col * 2048 + nc + khi * 8,
                 Wl + OFF_W2 + p * 16384 + blk * 1024);
        }
    }

    for (int c = 0; c < 64; c++) {
        int p = c & 1;
        __syncthreads();   // staged buf p ready; hid free from chunk c-1's S4

        if (c + 1 < 64) {  // stage next chunk into buf p^1 (overlaps compute)
            const int nc = (c + 1) * 32, q = p ^ 1;
#pragma unroll
            for (int it = 0; it < 4; it++) {
                int blk = it * 8 + wv;
                int idx = blk * 64 + l;
                int col = idx & 31, kh = idx >> 5;
                gl16(W1h + (size_t)(nc + col) * 512 + kh * 8,
                     Wl + q * 32768 + blk * 1024);
            }
#pragma unroll
            for (int it = 0; it < 2; it++) {
                int blk = it * 8 + wv;
                int idx = blk * 64 + l;
                int col = idx & 255, khi = idx >> 8;
                gl16(W2h + (size_t)col * 2048 + nc + khi * 8,
                     Wl + OFF_W2 + q * 16384 + blk * 1024);
            }
        }

        // ---- S3: hid[256][32] = relu(H_tile @ W1c^T + b1)
        {
            f32x4 s3[2][2] = {};
#pragma unroll
            for (int ks = 0; ks < 16; ks++) {
                f16x8 a0 = *(const f16x8*)(Hbase + ks * 32 + hi * 8);
                f16x8 a1 = *(const f16x8*)(Hbase + 16 * 512 + ks * 32 + hi * 8);
                f16x8 wb0 = *(const f16x8*)(Wl + p * 32768 +
                                            ((ks * 4 + hi) * 32 + lr) * 16);
                f16x8 wb1 = *(const f16x8*)(Wl + p * 32768 +
                                            ((ks * 4 + hi) * 32 + 16 + lr) * 16);
                s3[0][0] = MFMA16(a0, wb0, s3[0][0]);
                s3[0][1] = MFMA16(a0, wb1, s3[0][1]);
                s3[1][0] = MFMA16(a1, wb0, s3[1][0]);
                s3[1][1] = MFMA16(a1, wb1, s3[1][1]);
            }
            float bb0 = b1v[c * 32 + lr];
            float bb1 = b1v[c * 32 + 16 + lr];
            int k0 = (lr >> 3), k1 = ((16 + lr) >> 3);
            int sub = (lr & 7) * 2;
#pragma unroll
            for (int rf = 0; rf < 2; rf++) {
#pragma unroll
                for (int r = 0; r < 4; r++) {
                    int lrow = wv * 32 + rf * 16 + hi * 4 + r;
                    float v0 = fmaxf(s3[rf][0][r] + bb0, 0.f);
                    float v1 = fmaxf(s3[rf][1][r] + bb1, 0.f);
                    *(f16*)(Wl + OFF_HID + (k0 * 256 + lrow) * 16 + sub) = (f16)v0;
                    *(f16*)(Wl + OFF_HID + (k1 * 256 + lrow) * 16 + sub) = (f16)v1;
                }
            }
        }
        __syncthreads();   // hid complete

        // ---- S4: mc[32 rows][256] += hid(own rows) @ W2c^T
#pragma unroll
        for (int rf = 0; rf < 2; rf++) {
            int lrow = wv * 32 + rf * 16 + lr;
            f16x8 a = *(const f16x8*)(Wl + OFF_HID + (hi * 256 + lrow) * 16);
#pragma unroll
            for (int cf = 0; cf < 16; cf++) {
                f16x8 b = *(const f16x8*)(Wl + OFF_W2 + p * 16384 +
                                          (hi * 256 + cf * 16 + lr) * 16);
                mc[rf][cf] = MFMA16(a, b, mc[rf][cf]);
            }
        }
    }

    // ---- epilogue: GMM log-prob
    float quad[2][4] = {}, ls[2][4] = {}, xt[2][4];
#pragma unroll
    for (int rf = 0; rf < 2; rf++)
#pragma unroll
        for (int r = 0; r < 4; r++) {
            int m = M0 + wv * 32 + rf * 16 + hi * 4 + r;
            xt[rf][r] = x[(m & 511) * 128 + (m >> 9)];
        }
#pragma unroll
    for (int cf = 0; cf < 8; cf++) {
        int cc = cf * 16 + lr;
        float bm = b2[cc], bc = b2[128 + cc];
#pragma unroll
        for (int rf = 0; rf < 2; rf++)
#pragma unroll
            for (int r = 0; r < 4; r++) {
                float mean = mc[rf][cf][r] + bm;
                float cov  = mc[rf][cf + 8][r] + bc;
                float sp = log1pf(expf(-fabsf(cov))) + fmaxf(cov, 0.f);
                float d = xt[rf][r] - mean;
                quad[rf][r] += d * d * sp;
                ls[rf][r] += logf(sp);
            }
    }
#pragma unroll
    for (int mm = 1; mm < 16; mm <<= 1)
#pragma unroll
        for (int rf = 0; rf < 2; rf++)
#pragma unroll
            for (int r = 0; r < 4; r++) {
                quad[rf][r] += __shfl_xor(quad[rf][r], mm, 64);
                ls[rf][r]   += __shfl_xor(ls[rf][r], mm, 64);
            }
    if (lr == 0) {
#pragma unroll
        for (int rf = 0; rf < 2; rf++)
#pragma unroll
            for (int r = 0; r < 4; r++) {
                int m = M0 + wv * 32 + rf * 16 + hi * 4 + r;
                pcontrib[m] = -0.5f * (LOGDET_C + quad[rf][r]) - 0.5f * ls[rf][r];
            }
    }
}

// ---------------------------------------------------------------------------
__global__ void k_fin(const f16* __restrict__ h1last,
                      const float* __restrict__ pcontrib, float* __restrict__ out)
{
    int gid = blockIdx.x * 256 + threadIdx.x;
    for (int i = gid; i < HSZ; i += 131072) out[i] = (float)h1last[i];
    if (gid < 512) {
        float s = 0.f;
        for (int tt = 0; tt < 128; tt++) s += pcontrib[tt * 512 + gid];
        out[HSZ + gid] = s;
    }
}

// ---------------------------------------------------------------------------
extern "C" void kernel_launch(void* const* d_in, const int* in_sizes, int n_in,
                              void* d_out, int out_size, void* d_ws, size_t ws_size,
                              hipStream_t stream) {
    const float* x     = (const float*)d_in[0];
    const float* mask  = (const float*)d_in[1];
    const float* Wih0  = (const float*)d_in[2];
    const float* Whh0  = (const float*)d_in[3];
    const float* b_ih0 = (const float*)d_in[4];
    const float* b_hh0 = (const float*)d_in[5];
    const float* Wih1  = (const float*)d_in[6];
    const float* Whh1  = (const float*)d_in[7];
    const float* b_ih1 = (const float*)d_in[8];
    const float* b_hh1 = (const float*)d_in[9];
    const float* W1    = (const float*)d_in[10];
    const float* b1    = (const float*)d_in[11];
    const float* W2    = (const float*)d_in[12];
    const float* b2    = (const float*)d_in[13];

    char* ws = (char*)d_ws;
    size_t off = 0;
    auto take = [&](size_t bytes) { char* p = ws + off; off += (bytes + 255) & ~(size_t)255; return p; };
    float* base    = (float*)take(512 * 512 * 4);
    f16* Whh0h     = (f16*)take(HSZ * 2);
    f16* Wih1h     = (f16*)take(HSZ * 2);
    f16* Whh1h     = (f16*)take(HSZ * 2);
    f16* W1h       = (f16*)take(1048576 * 2);
    f16* W2h       = (f16*)take(524288 * 2);
    f16* h0buf     = (f16*)take(2 * HSZ * 2);
    f16* h1all     = (f16*)take((size_t)129 * HSZ * 2);
    float* pcontrib= (float*)take(128 * 512 * 4);
    f16* A         = (f16*)take(65536 * 2);
    f16* B1        = (f16*)take(65536 * 2);
    float* biasv   = (float*)take(512 * 4);
    int* slots     = (int*)take(4096 * 4);
    if (off > ws_size) return;

    k_conv<<<256, 256, 0, stream>>>(x, mask, Wih0, b_ih0, b_hh0, Whh0, Wih1, Whh1,
                                    W1, W2, A, B1, biasv, Whh0h, Wih1h, Whh1h,
                                    W1h, W2h, h1all, slots);
    k_base<<<256, 256, 0, stream>>>(A, B1, biasv, base, h0buf);
    k_rnn<<<256, 256, 0, stream>>>(h0buf, h1all, Whh0h, Wih1h, Whh1h,
                                   base, x, Wih0, b_ih1, b_hh1, slots);
    k_phaseB<<<256, 512, 0, stream>>>(h1all, W1h, W2h, b1, b2, x, pcontrib);
    k_fin<<<512, 256, 0, stream>>>(h1all + (size_t)128 * HSZ, pcontrib, (float*)d_out);
}

// Round 5
// 1274.827 us; speedup vs baseline: 4.3049x; 1.5925x over previous
//
#include <hip/hip_runtime.h>

typedef _Float16 f16;
typedef _Float16 f16x8 __attribute__((ext_vector_type(8)));
typedef float    f32x4 __attribute__((ext_vector_type(4)));
typedef unsigned int u32;
typedef u32 u32x4 __attribute__((ext_vector_type(4)));

#define MFMA16(a, b, c) __builtin_amdgcn_mfma_f32_16x16x32_f16((a), (b), (c), 0, 0, 0)

#define HSZ 262144            // 512*512
#define LOGDET_C 235.2482644923962f  // 128*log(2*pi)

// Coherent (cross-XCD) 16B load: reads at L3 coherence point.
__device__ __forceinline__ void ld16(u32x4& d, const f16* p) {
    asm volatile("global_load_dwordx4 %0, %1, off sc0 sc1" : "=v"(d) : "v"(p));
}
// Coherent 2B store: write-through to L3 coherence point.
__device__ __forceinline__ void st2(f16* p, f16 v) {
    u32 u = (u32)__builtin_bit_cast(unsigned short, v);
    asm volatile("global_store_short %0, %1, off sc0 sc1" :: "v"(p), "v"(u) : "memory");
}
// async global->LDS 16B (per-lane global src, wave-linear LDS dest)
__device__ __forceinline__ void gl16(const f16* g, char* l) {
    __builtin_amdgcn_global_load_lds(
        (const __attribute__((address_space(1))) u32*)g,
        (__attribute__((address_space(3))) u32*)l, 16, 0, 0);
}

// ---------------------------------------------------------------------------
// k_conv: conversions + small vectors (unchanged)
__global__ void k_conv(const float* __restrict__ x, const float* __restrict__ mask,
                       const float* __restrict__ Wih0,
                       const float* __restrict__ b_ih0, const float* __restrict__ b_hh0,
                       const float* __restrict__ Whh0, const float* __restrict__ Wih1,
                       const float* __restrict__ Whh1, const float* __restrict__ W1,
                       const float* __restrict__ W2,
                       f16* __restrict__ A, f16* __restrict__ B1,
                       float* __restrict__ biasv,
                       f16* __restrict__ Whh0h, f16* __restrict__ Wih1h,
                       f16* __restrict__ Whh1h, f16* __restrict__ W1h,
                       f16* __restrict__ W2h, f16* __restrict__ h1all,
                       int* __restrict__ slots)
{
    int gid = blockIdx.x * 256 + threadIdx.x;   // 0..65535
    {
        int c = gid >> 7, k = gid & 127;
        A[gid]  = (f16)(x[gid] * mask[k]);
        B1[gid] = (f16)Wih0[c * 257 + 1 + k];
    }
    if (gid < 512) {
        float s = b_ih0[gid] + b_hh0[gid];
        const float* wrow = Wih0 + gid * 257 + 129;
        for (int k = 0; k < 128; k++) s += mask[k] * wrow[k];
        biasv[gid] = s;
    }
    for (int i = gid; i < 262144; i += 65536) {
        Whh0h[i] = (f16)Whh0[i];
        Wih1h[i] = (f16)Wih1[i];
        Whh1h[i] = (f16)Whh1[i];
        h1all[i] = (f16)0.f;      // h1[t=-1]
    }
    for (int i = gid; i < 1048576; i += 65536) W1h[i] = (f16)W1[i];
    for (int i = gid; i < 524288;  i += 65536) W2h[i] = (f16)W2[i];
    if (gid < 4096) slots[gid] = 0;
}

// ---------------------------------------------------------------------------
// k_base: base = A @ B1^T + biasv ; h0buf[0] = tanh(base)  (unchanged)
__global__ __launch_bounds__(256) void k_base(const f16* __restrict__ A,
                                              const f16* __restrict__ B1,
                                              const float* __restrict__ biasv,
                                              float* __restrict__ base,
                                              f16* __restrict__ h0buf)
{
    __shared__ float part[4][32][32];
    int tid = threadIdx.x;
    int w = tid >> 6, l = tid & 63;
    int R0 = (blockIdx.x >> 4) * 32, C0 = (blockIdx.x & 15) * 32;
    int lr = l & 15, hi = l >> 4;

    const f16* a0p = A  + (R0 + lr) * 128 + w * 32 + hi * 8;
    const f16* b0p = B1 + (C0 + lr) * 128 + w * 32 + hi * 8;
    f16x8 a0 = *(const f16x8*)(a0p);
    f16x8 a1 = *(const f16x8*)(a0p + 16 * 128);
    f16x8 b0 = *(const f16x8*)(b0p);
    f16x8 b1 = *(const f16x8*)(b0p + 16 * 128);
    f32x4 z = {0.f, 0.f, 0.f, 0.f};
    f32x4 acc00 = MFMA16(a0, b0, z);
    f32x4 acc01 = MFMA16(a0, b1, z);
    f32x4 acc10 = MFMA16(a1, b0, z);
    f32x4 acc11 = MFMA16(a1, b1, z);
#pragma unroll
    for (int r = 0; r < 4; r++) {
        part[w][hi * 4 + r][lr]           = acc00[r];
        part[w][hi * 4 + r][16 + lr]      = acc01[r];
        part[w][16 + hi * 4 + r][lr]      = acc10[r];
        part[w][16 + hi * 4 + r][16 + lr] = acc11[r];
    }
    __syncthreads();
    int rr = tid >> 3, c0 = (tid & 7) * 4;
    int gr = R0 + rr;
#pragma unroll
    for (int cc = 0; cc < 4; cc++) {
        int gc = C0 + c0 + cc;
        float s = part[0][rr][c0 + cc] + part[1][rr][c0 + cc] +
                  part[2][rr][c0 + cc] + part[3][rr][c0 + cc] + biasv[gc];
        base[gr * 512 + gc] = s;
        h0buf[gr * 512 + gc] = (f16)tanhf(s);
    }
}

// ---------------------------------------------------------------------------
// Persistent recurrence kernel (unchanged from round 3).
__global__ __launch_bounds__(256, 1) void k_rnn(
    f16* __restrict__ h0buf, f16* __restrict__ h1all,
    const f16* __restrict__ Whh0h, const f16* __restrict__ Wih1h,
    const f16* __restrict__ Whh1h,
    const float* __restrict__ base, const float* __restrict__ x,
    const float* __restrict__ Wih0, const float* __restrict__ b_ih1,
    const float* __restrict__ b_hh1, int* __restrict__ slots)
{
    __shared__ __align__(16) f16 Wl[3 * 32 * 512];   // 96 KB, XOR-swizzled
    int tid = threadIdx.x;
    int w = tid >> 6, l = tid & 63;
    int ci = blockIdx.x >> 4;        // cluster (row block)
    int cj = blockIdx.x & 15;        // col block
    int R0 = ci * 32, C0 = cj * 32;

    {
        const f16* srcs[3] = { Whh0h, Wih1h, Whh1h };
        for (int m = 0; m < 3; m++) {
            const f16* S = srcs[m] + (size_t)C0 * 512;
            for (int cch = tid; cch < 2048; cch += 256) {
                int col = cch >> 6, kc = cch & 63;
                f16x8 v = *(const f16x8*)(S + col * 512 + kc * 8);
                int byte = m * 32768 + col * 1024 + kc * 16;
                byte ^= (col & 7) << 4;
                *(f16x8*)((char*)Wl + byte) = v;
            }
        }
    }
    __syncthreads();

    int lr = l & 15, hi = l >> 4;
    int r_lo = (w >> 1) * 16, c_lo = (w & 1) * 16;
    int outrow = R0 + r_lo + hi * 4;
    int outcolg = C0 + c_lo + lr;
    int colL = c_lo + lr;

    float basef[4];
#pragma unroll
    for (int r = 0; r < 4; r++) basef[r] = base[(outrow + r) * 512 + outcolg];
    float w0 = Wih0[outcolg * 257];
    float bsum = b_ih1[outcolg] + b_hh1[outcolg];

    int* myslot = slots + (ci * 16 + cj) * 16;
    int* peerslot = slots + (ci * 16 + (l & 15)) * 16;

#define LDB(m, k0) (*(const f16x8*)((char*)Wl + \
        ((((m) * 32768 + colL * 1024 + (k0) * 2)) ^ ((colL & 7) << 4))))

    for (int p = 0; p < 128; p++) {
        const f16* H0 = h0buf + (p & 1) * HSZ;
        const f16* H1 = h1all + (size_t)p * HSZ;
        const f16* ap = H0 + (R0 + r_lo + lr) * 512 + hi * 8;
        const f16* bp = H1 + (R0 + r_lo + lr) * 512 + hi * 8;

        float xprev[4];
#pragma unroll
        for (int r = 0; r < 4; r++) xprev[r] = x[(outrow + r) * 128 + p];

        u32x4 ra0[16], ra1[16];
        __builtin_amdgcn_sched_barrier(0);
#pragma unroll
        for (int f = 0; f < 16; f++) ld16(ra0[f], ap + f * 32);
#pragma unroll
        for (int f = 0; f < 16; f++) ld16(ra1[f], bp + f * 32);
        asm volatile("s_waitcnt vmcnt(0)" ::: "memory");
        __builtin_amdgcn_sched_barrier(0);

        f32x4 acc1 = {0.f, 0.f, 0.f, 0.f}, acc0n = acc1;
#pragma unroll
        for (int f = 0; f < 16; f++) {
            f16x8 a = __builtin_bit_cast(f16x8, ra0[f]);
            acc1  = MFMA16(a, LDB(1, f * 32 + hi * 8), acc1);
            acc0n = MFMA16(a, LDB(0, f * 32 + hi * 8), acc0n);
        }
#pragma unroll
        for (int f = 0; f < 16; f++) {
            f16x8 a = __builtin_bit_cast(f16x8, ra1[f]);
            acc1 = MFMA16(a, LDB(2, f * 32 + hi * 8), acc1);
        }

        f16* H1o = h1all + (size_t)(p + 1) * HSZ;
        f16* H0o = h0buf + ((p + 1) & 1) * HSZ;
#pragma unroll
        for (int r = 0; r < 4; r++) {
            f16 v1 = (f16)tanhf(acc1[r] + bsum);
            f16 v0 = (f16)tanhf(acc0n[r] + basef[r] + xprev[r] * w0);
            st2(H1o + (outrow + r) * 512 + outcolg, v1);
            st2(H0o + (outrow + r) * 512 + outcolg, v0);
        }

        if (p < 127) {
            asm volatile("s_waitcnt vmcnt(0)" ::: "memory");
            __syncthreads();
            if (w == 0) {
                int target = p + 1;
                if (l == 0)
                    __hip_atomic_store(myslot, target, __ATOMIC_RELAXED,
                                       __HIP_MEMORY_SCOPE_AGENT);
                int ok;
                do {
                    int v = 0x7fffffff;
                    if (l < 16)
                        v = __hip_atomic_load(peerslot, __ATOMIC_RELAXED,
                                              __HIP_MEMORY_SCOPE_AGENT);
                    ok = __all(v >= target);
                } while (!ok);
            }
            __syncthreads();
        }
    }
#undef LDB
}

// ---------------------------------------------------------------------------
// Phase B v3: M-tile 16 rows/wave (128/wg, 512 wgs x 512 thr).
// H (A-operand) held in registers for the whole kernel (16 x f16x8 = 64 VGPR,
// loaded ONCE) -> no H re-reads, no L2 thrash. mc = 16 x f32x4 = 64 VGPR ->
// no spills (round-4 spill traffic was 1.6 GB W + 1.6 GB R).
// NC chunk = 32, W1/W2 double-buffered via global_load_lds (k-major layout,
// 2-way-free ds_reads). hid scratch [128][40] padded (2-way-free).
// LDS = 64K + 32K + 10K = 106 KB -> 1 wg/CU, 2 waves/SIMD.
__global__ __launch_bounds__(512, 2) void k_phaseB(const f16* __restrict__ h1all,
                                                   const f16* __restrict__ W1h,
                                                   const f16* __restrict__ W2h,
                                                   const float* __restrict__ b1v,
                                                   const float* __restrict__ b2,
                                                   const float* __restrict__ x,
                                                   float* __restrict__ pcontrib)
{
    __shared__ __align__(16) char Wl[108544];
    const int OFF_W2 = 65536, OFF_HID = 98304;

    int tid = threadIdx.x;
    int wv = tid >> 6, l = tid & 63;
    int lr = l & 15, hi = l >> 4;
    int M0 = blockIdx.x * 128;

    // ---- load this lane's A-fragments of H once (row = M0 + wv*16 + lr)
    const f16* Hrow = h1all + HSZ + (size_t)(M0 + wv * 16 + lr) * 512;
    f16x8 afrag[16];
#pragma unroll
    for (int ks = 0; ks < 16; ks++)
        afrag[ks] = *(const f16x8*)(Hrow + ks * 32 + hi * 8);

    f32x4 mc[16] = {};

    // prologue: stage chunk 0 into buf 0
    {
#pragma unroll
        for (int it = 0; it < 4; it++) {
            int idx = it * 512 + tid;           // 0..2047
            gl16(W1h + (size_t)(idx & 31) * 512 + (idx >> 5) * 8,
                 Wl + idx * 16);
        }
#pragma unroll
        for (int it = 0; it < 2; it++) {
            int idx = it * 512 + tid;           // 0..1023
            gl16(W2h + (size_t)(idx & 255) * 2048 + (idx >> 8) * 8,
                 Wl + OFF_W2 + idx * 16);
        }
    }

    for (int c = 0; c < 64; c++) {
        int p = c & 1;
        __syncthreads();   // staged buf p ready; hid free from chunk c-1's S4

        if (c + 1 < 64) {  // stage next chunk into buf p^1 (overlaps compute)
            const int nc = (c + 1) * 32, q = p ^ 1;
#pragma unroll
            for (int it = 0; it < 4; it++) {
                int idx = it * 512 + tid;
                gl16(W1h + (size_t)(nc + (idx & 31)) * 512 + (idx >> 5) * 8,
                     Wl + q * 32768 + idx * 16);
            }
#pragma unroll
            for (int it = 0; it < 2; it++) {
                int idx = it * 512 + tid;
                gl16(W2h + (size_t)(idx & 255) * 2048 + nc + (idx >> 8) * 8,
                     Wl + OFF_W2 + q * 16384 + idx * 16);
            }
        }

        // ---- S3: hid[16 rows][32 cols] = relu(Hwave @ W1c^T + b1)
        {
            f32x4 s3a = {0.f, 0.f, 0.f, 0.f}, s3b = s3a;
#pragma unroll
            for (int ks = 0; ks < 16; ks++) {
                f16x8 wb0 = *(const f16x8*)(Wl + p * 32768 +
                                            ((ks * 4 + hi) * 32 + lr) * 16);
                f16x8 wb1 = *(const f16x8*)(Wl + p * 32768 +
                                            ((ks * 4 + hi) * 32 + 16 + lr) * 16);
                s3a = MFMA16(afrag[ks], wb0, s3a);
                s3b = MFMA16(afrag[ks], wb1, s3b);
            }
            float bb0 = b1v[c * 32 + lr];
            float bb1 = b1v[c * 32 + 16 + lr];
#pragma unroll
            for (int r = 0; r < 4; r++) {
                int lrow = wv * 16 + hi * 4 + r;
                *(f16*)(Wl + OFF_HID + (lrow * 40 + lr) * 2) =
                    (f16)fmaxf(s3a[r] + bb0, 0.f);
                *(f16*)(Wl + OFF_HID + (lrow * 40 + 16 + lr) * 2) =
                    (f16)fmaxf(s3b[r] + bb1, 0.f);
            }
        }
        __syncthreads();   // hid complete

        // ---- S4: mc[16 rows][256] += hid(own rows) @ W2c^T
        {
            f16x8 a = *(const f16x8*)(Wl + OFF_HID +
                                      ((wv * 16 + lr) * 40 + hi * 8) * 2);
#pragma unroll
            for (int cf = 0; cf < 16; cf++) {
                f16x8 b = *(const f16x8*)(Wl + OFF_W2 + p * 16384 +
                                          (hi * 256 + cf * 16 + lr) * 16);
                mc[cf] = MFMA16(a, b, mc[cf]);
            }
        }
    }

    // ---- epilogue: GMM log-prob
    float quad[4] = {}, ls[4] = {}, xt[4];
#pragma unroll
    for (int r = 0; r < 4; r++) {
        int m = M0 + wv * 16 + hi * 4 + r;
        xt[r] = x[(m & 511) * 128 + (m >> 9)];
    }
#pragma unroll
    for (int cf = 0; cf < 8; cf++) {
        int cc = cf * 16 + lr;
        float bm = b2[cc], bc = b2[128 + cc];
#pragma unroll
        for (int r = 0; r < 4; r++) {
            float mean = mc[cf][r] + bm;
            float cov  = mc[cf + 8][r] + bc;
            float sp = log1pf(expf(-fabsf(cov))) + fmaxf(cov, 0.f);
            float d = xt[r] - mean;
            quad[r] += d * d * sp;
            ls[r] += logf(sp);
        }
    }
#pragma unroll
    for (int mm = 1; mm < 16; mm <<= 1)
#pragma unroll
        for (int r = 0; r < 4; r++) {
            quad[r] += __shfl_xor(quad[r], mm, 64);
            ls[r]   += __shfl_xor(ls[r], mm, 64);
        }
    if (lr == 0) {
#pragma unroll
        for (int r = 0; r < 4; r++) {
            int m = M0 + wv * 16 + hi * 4 + r;
            pcontrib[m] = -0.5f * (LOGDET_C + quad[r]) - 0.5f * ls[r];
        }
    }
}

// ---------------------------------------------------------------------------
__global__ void k_fin(const f16* __restrict__ h1last,
                      const float* __restrict__ pcontrib, float* __restrict__ out)
{
    int gid = blockIdx.x * 256 + threadIdx.x;
    for (int i = gid; i < HSZ; i += 131072) out[i] = (float)h1last[i];
    if (gid < 512) {
        float s = 0.f;
        for (int tt = 0; tt < 128; tt++) s += pcontrib[tt * 512 + gid];
        out[HSZ + gid] = s;
    }
}

// ---------------------------------------------------------------------------
extern "C" void kernel_launch(void* const* d_in, const int* in_sizes, int n_in,
                              void* d_out, int out_size, void* d_ws, size_t ws_size,
                              hipStream_t stream) {
    const float* x     = (const float*)d_in[0];
    const float* mask  = (const float*)d_in[1];
    const float* Wih0  = (const float*)d_in[2];
    const float* Whh0  = (const float*)d_in[3];
    const float* b_ih0 = (const float*)d_in[4];
    const float* b_hh0 = (const float*)d_in[5];
    const float* Wih1  = (const float*)d_in[6];
    const float* Whh1  = (const float*)d_in[7];
    const float* b_ih1 = (const float*)d_in[8];
    const float* b_hh1 = (const float*)d_in[9];
    const float* W1    = (const float*)d_in[10];
    const float* b1    = (const float*)d_in[11];
    const float* W2    = (const float*)d_in[12];
    const float* b2    = (const float*)d_in[13];

    char* ws = (char*)d_ws;
    size_t off = 0;
    auto take = [&](size_t bytes) { char* p = ws + off; off += (bytes + 255) & ~(size_t)255; return p; };
    float* base    = (float*)take(512 * 512 * 4);
    f16* Whh0h     = (f16*)take(HSZ * 2);
    f16* Wih1h     = (f16*)take(HSZ * 2);
    f16* Whh1h     = (f16*)take(HSZ * 2);
    f16* W1h       = (f16*)take(1048576 * 2);
    f16* W2h       = (f16*)take(524288 * 2);
    f16* h0buf     = (f16*)take(2 * HSZ * 2);
    f16* h1all     = (f16*)take((size_t)129 * HSZ * 2);
    float* pcontrib= (float*)take(128 * 512 * 4);
    f16* A         = (f16*)take(65536 * 2);
    f16* B1        = (f16*)take(65536 * 2);
    float* biasv   = (float*)take(512 * 4);
    int* slots     = (int*)take(4096 * 4);
    if (off > ws_size) return;

    k_conv<<<256, 256, 0, stream>>>(x, mask, Wih0, b_ih0, b_hh0, Whh0, Wih1, Whh1,
                                    W1, W2, A, B1, biasv, Whh0h, Wih1h, Whh1h,
                                    W1h, W2h, h1all, slots);
    k_base<<<256, 256, 0, stream>>>(A, B1, biasv, base, h0buf);
    k_rnn<<<256, 256, 0, stream>>>(h0buf, h1all, Whh0h, Wih1h, Whh1h,
                                   base, x, Wih0, b_ih1, b_hh1, slots);
    k_phaseB<<<512, 512, 0, stream>>>(h1all, W1h, W2h, b1, b2, x, pcontrib);
    k_fin<<<512, 256, 0, stream>>>(h1all + (size_t)128 * HSZ, pcontrib, (float*)d_out);
}

// Round 7
// 1101.076 us; speedup vs baseline: 4.9842x; 1.1578x over previous
//
#include <hip/hip_runtime.h>

typedef _Float16 f16;
typedef _Float16 f16x8 __attribute__((ext_vector_type(8)));
typedef float    f32x4 __attribute__((ext_vector_type(4)));
typedef unsigned int u32;
typedef u32 u32x4 __attribute__((ext_vector_type(4)));

#define MFMA16(a, b, c) __builtin_amdgcn_mfma_f32_16x16x32_f16((a), (b), (c), 0, 0, 0)

#define HSZ 262144            // 512*512
#define LOGDET_C 235.2482644923962f  // 128*log(2*pi)

// ---- memory access primitives -------------------------------------------
// _n (normal): cacheable load; ONLY used on addresses that are virgin within
//              this kernel (monotonic slabs) -> no staleness possible.
// _s (sc0 sc1): L3 coherence point; proven cross-XCD-safe (rounds 3-5).
__device__ __forceinline__ void ld16_n(u32x4& d, const f16* p) {
    asm volatile("global_load_dwordx4 %0, %1, off" : "=v"(d) : "v"(p));
}
__device__ __forceinline__ void ld16_s(u32x4& d, const f16* p) {
    asm volatile("global_load_dwordx4 %0, %1, off sc0 sc1" : "=v"(d) : "v"(p));
}
__device__ __forceinline__ void st2_s(f16* p, f16 v) {
    u32 u = (u32)__builtin_bit_cast(unsigned short, v);
    asm volatile("global_store_short %0, %1, off sc0 sc1" :: "v"(p), "v"(u) : "memory");
}
__device__ __forceinline__ void sti_s(int* p, int v) {
    asm volatile("global_store_dword %0, %1, off sc0 sc1" :: "v"(p), "v"(v) : "memory");
}
__device__ __forceinline__ int ldi_s(const int* p) {
    int v;
    asm volatile("global_load_dword %0, %1, off sc0 sc1\ns_waitcnt vmcnt(0)"
                 : "=v"(v) : "v"(p) : "memory");
    return v;
}
// async global->LDS 16B (per-lane global src, wave-linear LDS dest)
__device__ __forceinline__ void gl16(const f16* g, char* l) {
    __builtin_amdgcn_global_load_lds(
        (const __attribute__((address_space(1))) u32*)g,
        (__attribute__((address_space(3))) u32*)l, 16, 0, 0);
}
// tanh via HW exp2+rcp: tanh(x) = 1 - 2/(exp2(x*2/ln2)+1). |err| ~1e-6.
__device__ __forceinline__ float tanh_fast(float x) {
    float e = __builtin_amdgcn_exp2f(x * 2.8853900817779268f);
    return 1.f - 2.f * __builtin_amdgcn_rcpf(e + 1.f);
}

// ---------------------------------------------------------------------------
// k_conv: conversions + small vectors; init slots=0.
__global__ void k_conv(const float* __restrict__ x, const float* __restrict__ mask,
                       const float* __restrict__ Wih0,
                       const float* __restrict__ b_ih0, const float* __restrict__ b_hh0,
                       const float* __restrict__ Whh0, const float* __restrict__ Wih1,
                       const float* __restrict__ Whh1, const float* __restrict__ W1,
                       const float* __restrict__ W2,
                       f16* __restrict__ A, f16* __restrict__ B1,
                       float* __restrict__ biasv,
                       f16* __restrict__ Whh0h, f16* __restrict__ Wih1h,
                       f16* __restrict__ Whh1h, f16* __restrict__ W1h,
                       f16* __restrict__ W2h, f16* __restrict__ h1all,
                       int* __restrict__ slots)
{
    int gid = blockIdx.x * 256 + threadIdx.x;   // 0..65535
    {
        int c = gid >> 7, k = gid & 127;
        A[gid]  = (f16)(x[gid] * mask[k]);
        B1[gid] = (f16)Wih0[c * 257 + 1 + k];
    }
    if (gid < 512) {
        float s = b_ih0[gid] + b_hh0[gid];
        const float* wrow = Wih0 + gid * 257 + 129;
        for (int k = 0; k < 128; k++) s += mask[k] * wrow[k];
        biasv[gid] = s;
    }
    for (int i = gid; i < 262144; i += 65536) {
        Whh0h[i] = (f16)Whh0[i];
        Wih1h[i] = (f16)Wih1[i];
        Whh1h[i] = (f16)Whh1[i];
        h1all[i] = (f16)0.f;      // h1[t=-1]
    }
    for (int i = gid; i < 1048576; i += 65536) W1h[i] = (f16)W1[i];
    for (int i = gid; i < 524288;  i += 65536) W2h[i] = (f16)W2[i];
    if (gid < 4096) slots[gid] = 0;
}

// ---------------------------------------------------------------------------
// k_base: base = A @ B1^T + biasv ; h0 slab0 = tanh(base)
__global__ __launch_bounds__(256) void k_base(const f16* __restrict__ A,
                                              const f16* __restrict__ B1,
                                              const float* __restrict__ biasv,
                                              float* __restrict__ base,
                                              f16* __restrict__ h0s0)
{
    __shared__ float part[4][32][32];
    int tid = threadIdx.x;
    int w = tid >> 6, l = tid & 63;
    int R0 = (blockIdx.x >> 4) * 32, C0 = (blockIdx.x & 15) * 32;
    int lr = l & 15, hi = l >> 4;

    const f16* a0p = A  + (R0 + lr) * 128 + w * 32 + hi * 8;
    const f16* b0p = B1 + (C0 + lr) * 128 + w * 32 + hi * 8;
    f16x8 a0 = *(const f16x8*)(a0p);
    f16x8 a1 = *(const f16x8*)(a0p + 16 * 128);
    f16x8 b0 = *(const f16x8*)(b0p);
    f16x8 b1 = *(const f16x8*)(b0p + 16 * 128);
    f32x4 z = {0.f, 0.f, 0.f, 0.f};
    f32x4 acc00 = MFMA16(a0, b0, z);
    f32x4 acc01 = MFMA16(a0, b1, z);
    f32x4 acc10 = MFMA16(a1, b0, z);
    f32x4 acc11 = MFMA16(a1, b1, z);
#pragma unroll
    for (int r = 0; r < 4; r++) {
        part[w][hi * 4 + r][lr]           = acc00[r];
        part[w][hi * 4 + r][16 + lr]      = acc01[r];
        part[w][16 + hi * 4 + r][lr]      = acc10[r];
        part[w][16 + hi * 4 + r][16 + lr] = acc11[r];
    }
    __syncthreads();
    int rr = tid >> 3, c0 = (tid & 7) * 4;
    int gr = R0 + rr;
#pragma unroll
    for (int cc = 0; cc < 4; cc++) {
        int gc = C0 + c0 + cc;
        float s = part[0][rr][c0 + cc] + part[1][rr][c0 + cc] +
                  part[2][rr][c0 + cc] + part[3][rr][c0 + cc] + biasv[gc];
        base[gr * 512 + gc] = s;
        h0s0[gr * 512 + gc] = (f16)tanh_fast(s);
    }
}

// ---------------------------------------------------------------------------
// Persistent recurrence kernel. 256 wgs, 1 wg/CU (96KB LDS). Cluster = 16 wgs
// sharing bid&7 (L2-locality heuristic only — correctness is placement-
// independent). Protocol:
//   stores: sc0 sc1 write-through to L3 (proven r3-r5).
//   slot barrier: sc0 sc1 (byte-identical to r3-r5).
//   h1 loads: NORMAL cacheable — h1all is monotonic (slab per phase), every
//     address virgin within this kernel -> L1/L2 miss mandatory -> allocates
//     from L3 (fresh), cluster-mates on the same XCD then share the L2 line.
//   h0 loads: same IF the host allocated 129 monotonic slabs (H0F=true);
//     else 2-slab ring + sc0 sc1 reads (exact r5 behavior).
template<bool H0F>
__global__ __launch_bounds__(256, 1) void k_rnn(
    f16* __restrict__ h0all, f16* __restrict__ h1all,
    const f16* __restrict__ Whh0h, const f16* __restrict__ Wih1h,
    const f16* __restrict__ Whh1h,
    const float* __restrict__ base, const float* __restrict__ x,
    const float* __restrict__ Wih0, const float* __restrict__ b_ih1,
    const float* __restrict__ b_hh1, int* __restrict__ slots)
{
    constexpr int PMASK = H0F ? 255 : 1;
    __shared__ __align__(16) f16 Wl[3 * 32 * 512];   // 96 KB, XOR-swizzled
    int tid = threadIdx.x;
    int w = tid >> 6, l = tid & 63;
    int bid = blockIdx.x;
    int sub = (bid >> 3) & 1, cj = bid >> 4;
    int cluster = (bid & 7) * 2 + sub;       // cluster-mates share bid&7
    int R0 = cluster * 32, C0 = cj * 32;

    // ---- stage weight col-slices into LDS with bank-conflict swizzle
    {
        const f16* srcs[3] = { Whh0h, Wih1h, Whh1h };
        for (int m = 0; m < 3; m++) {
            const f16* S = srcs[m] + (size_t)C0 * 512;
            for (int cch = tid; cch < 2048; cch += 256) {
                int col = cch >> 6, kc = cch & 63;
                f16x8 v = *(const f16x8*)(S + col * 512 + kc * 8);
                int byte = m * 32768 + col * 1024 + kc * 16;
                byte ^= (col & 7) << 4;
                *(f16x8*)((char*)Wl + byte) = v;
            }
        }
    }
    __syncthreads();

    int lr = l & 15, hi = l >> 4;
    int r_lo = (w >> 1) * 16, c_lo = (w & 1) * 16;
    int outrow = R0 + r_lo + hi * 4;        // +r for r in 0..3
    int outcolg = C0 + c_lo + lr;           // global output col
    int colL = c_lo + lr;                   // local col within wg slice

    float basef[4];
#pragma unroll
    for (int r = 0; r < 4; r++) basef[r] = base[(outrow + r) * 512 + outcolg];
    float w0 = Wih0[outcolg * 257];
    float bsum = b_ih1[outcolg] + b_hh1[outcolg];

    int* myslot = slots + (cluster * 16 + cj) * 16;          // 64B-padded slot
    int* peerslot = slots + (cluster * 16 + (l & 15)) * 16;  // lanes 0..15 poll

#define LDB(m, k0) (*(const f16x8*)((char*)Wl + \
        ((((m) * 32768 + colL * 1024 + (k0) * 2)) ^ ((colL & 7) << 4))))

    for (int p = 0; p < 128; p++) {
        const f16* H0 = h0all + (size_t)(p & PMASK) * HSZ;
        const f16* H1 = h1all + (size_t)p * HSZ;
        const f16* ap = H0 + (R0 + r_lo + lr) * 512 + hi * 8;
        const f16* bp = H1 + (R0 + r_lo + lr) * 512 + hi * 8;

        float xprev[4];
#pragma unroll
        for (int r = 0; r < 4; r++) xprev[r] = x[(outrow + r) * 128 + p];

        u32x4 ra0[16], ra1[16];
        __builtin_amdgcn_sched_barrier(0);
#pragma unroll
        for (int f = 0; f < 16; f++) {
            if constexpr (H0F) ld16_n(ra0[f], ap + f * 32);
            else               ld16_s(ra0[f], ap + f * 32);
        }
#pragma unroll
        for (int f = 0; f < 16; f++) ld16_n(ra1[f], bp + f * 32);
        // h0 batch (first 16) retired; start M1/M2 while h1 flies
        asm volatile("s_waitcnt vmcnt(16)" ::: "memory");
        __builtin_amdgcn_sched_barrier(0);

        f32x4 acc1 = {0.f, 0.f, 0.f, 0.f}, acc0n = acc1;
#pragma unroll
        for (int f = 0; f < 16; f++) {
            f16x8 a = __builtin_bit_cast(f16x8, ra0[f]);
            acc1  = MFMA16(a, LDB(1, f * 32 + hi * 8), acc1);
            acc0n = MFMA16(a, LDB(0, f * 32 + hi * 8), acc0n);
        }
        asm volatile("s_waitcnt vmcnt(0)" ::: "memory");
        __builtin_amdgcn_sched_barrier(0);
#pragma unroll
        for (int f = 0; f < 16; f++) {
            f16x8 a = __builtin_bit_cast(f16x8, ra1[f]);
            acc1 = MFMA16(a, LDB(2, f * 32 + hi * 8), acc1);
        }

        f16* H1o = h1all + (size_t)(p + 1) * HSZ;
        f16* H0o = h0all + (size_t)((p + 1) & PMASK) * HSZ;
#pragma unroll
        for (int r = 0; r < 4; r++) {
            f16 v1 = (f16)tanh_fast(acc1[r] + bsum);
            f16 v0 = (f16)tanh_fast(acc0n[r] + basef[r] + xprev[r] * w0);
            st2_s(H1o + (outrow + r) * 512 + outcolg, v1);
            st2_s(H0o + (outrow + r) * 512 + outcolg, v0);
        }

        if (p < 127) {
            // drain write-through stores, then cluster barrier (r3-r5 proven)
            asm volatile("s_waitcnt vmcnt(0)" ::: "memory");
            __syncthreads();
            if (w == 0) {
                int target = p + 1;
                if (l == 0) sti_s(myslot, target);
                int v;
                do { v = (l < 16) ? ldi_s(peerslot) : target; }
                while (!__all(v >= target));
            }
            __syncthreads();
        }
    }
#undef LDB
}

// ---------------------------------------------------------------------------
// Phase B v3 (unchanged from round 5)
__global__ __launch_bounds__(512, 2) void k_phaseB(const f16* __restrict__ h1all,
                                                   const f16* __restrict__ W1h,
                                                   const f16* __restrict__ W2h,
                                                   const float* __restrict__ b1v,
                                                   const float* __restrict__ b2,
                                                   const float* __restrict__ x,
                                                   float* __restrict__ pcontrib)
{
    __shared__ __align__(16) char Wl[108544];
    const int OFF_W2 = 65536, OFF_HID = 98304;

    int tid = threadIdx.x;
    int wv = tid >> 6, l = tid & 63;
    int lr = l & 15, hi = l >> 4;
    int M0 = blockIdx.x * 128;

    const f16* Hrow = h1all + HSZ + (size_t)(M0 + wv * 16 + lr) * 512;
    f16x8 afrag[16];
#pragma unroll
    for (int ks = 0; ks < 16; ks++)
        afrag[ks] = *(const f16x8*)(Hrow + ks * 32 + hi * 8);

    f32x4 mc[16] = {};

    {
#pragma unroll
        for (int it = 0; it < 4; it++) {
            int idx = it * 512 + tid;
            gl16(W1h + (size_t)(idx & 31) * 512 + (idx >> 5) * 8,
                 Wl + idx * 16);
        }
#pragma unroll
        for (int it = 0; it < 2; it++) {
            int idx = it * 512 + tid;
            gl16(W2h + (size_t)(idx & 255) * 2048 + (idx >> 8) * 8,
                 Wl + OFF_W2 + idx * 16);
        }
    }

    for (int c = 0; c < 64; c++) {
        int p = c & 1;
        __syncthreads();

        if (c + 1 < 64) {
            const int nc = (c + 1) * 32, q = p ^ 1;
#pragma unroll
            for (int it = 0; it < 4; it++) {
                int idx = it * 512 + tid;
                gl16(W1h + (size_t)(nc + (idx & 31)) * 512 + (idx >> 5) * 8,
                     Wl + q * 32768 + idx * 16);
            }
#pragma unroll
            for (int it = 0; it < 2; it++) {
                int idx = it * 512 + tid;
                gl16(W2h + (size_t)(idx & 255) * 2048 + nc + (idx >> 8) * 8,
                     Wl + OFF_W2 + q * 16384 + idx * 16);
            }
        }

        {
            f32x4 s3a = {0.f, 0.f, 0.f, 0.f}, s3b = s3a;
#pragma unroll
            for (int ks = 0; ks < 16; ks++) {
                f16x8 wb0 = *(const f16x8*)(Wl + p * 32768 +
                                            ((ks * 4 + hi) * 32 + lr) * 16);
                f16x8 wb1 = *(const f16x8*)(Wl + p * 32768 +
                                            ((ks * 4 + hi) * 32 + 16 + lr) * 16);
                s3a = MFMA16(afrag[ks], wb0, s3a);
                s3b = MFMA16(afrag[ks], wb1, s3b);
            }
            float bb0 = b1v[c * 32 + lr];
            float bb1 = b1v[c * 32 + 16 + lr];
#pragma unroll
            for (int r = 0; r < 4; r++) {
                int lrow = wv * 16 + hi * 4 + r;
                *(f16*)(Wl + OFF_HID + (lrow * 40 + lr) * 2) =
                    (f16)fmaxf(s3a[r] + bb0, 0.f);
                *(f16*)(Wl + OFF_HID + (lrow * 40 + 16 + lr) * 2) =
                    (f16)fmaxf(s3b[r] + bb1, 0.f);
            }
        }
        __syncthreads();

        {
            f16x8 a = *(const f16x8*)(Wl + OFF_HID +
                                      ((wv * 16 + lr) * 40 + hi * 8) * 2);
#pragma unroll
            for (int cf = 0; cf < 16; cf++) {
                f16x8 b = *(const f16x8*)(Wl + OFF_W2 + p * 16384 +
                                          (hi * 256 + cf * 16 + lr) * 16);
                mc[cf] = MFMA16(a, b, mc[cf]);
            }
        }
    }

    float quad[4] = {}, ls[4] = {}, xt[4];
#pragma unroll
    for (int r = 0; r < 4; r++) {
        int m = M0 + wv * 16 + hi * 4 + r;
        xt[r] = x[(m & 511) * 128 + (m >> 9)];
    }
#pragma unroll
    for (int cf = 0; cf < 8; cf++) {
        int cc = cf * 16 + lr;
        float bm = b2[cc], bc = b2[128 + cc];
#pragma unroll
        for (int r = 0; r < 4; r++) {
            float mean = mc[cf][r] + bm;
            float cov  = mc[cf + 8][r] + bc;
            float sp = log1pf(expf(-fabsf(cov))) + fmaxf(cov, 0.f);
            float d = xt[r] - mean;
            quad[r] += d * d * sp;
            ls[r] += logf(sp);
        }
    }
#pragma unroll
    for (int mm = 1; mm < 16; mm <<= 1)
#pragma unroll
        for (int r = 0; r < 4; r++) {
            quad[r] += __shfl_xor(quad[r], mm, 64);
            ls[r]   += __shfl_xor(ls[r], mm, 64);
        }
    if (lr == 0) {
#pragma unroll
        for (int r = 0; r < 4; r++) {
            int m = M0 + wv * 16 + hi * 4 + r;
            pcontrib[m] = -0.5f * (LOGDET_C + quad[r]) - 0.5f * ls[r];
        }
    }
}

// ---------------------------------------------------------------------------
__global__ void k_fin(const f16* __restrict__ h1last,
                      const float* __restrict__ pcontrib, float* __restrict__ out)
{
    int gid = blockIdx.x * 256 + threadIdx.x;
    for (int i = gid; i < HSZ; i += 131072) out[i] = (float)h1last[i];
    if (gid < 512) {
        float s = 0.f;
        for (int tt = 0; tt < 128; tt++) s += pcontrib[tt * 512 + gid];
        out[HSZ + gid] = s;
    }
}

// ---------------------------------------------------------------------------
extern "C" void kernel_launch(void* const* d_in, const int* in_sizes, int n_in,
                              void* d_out, int out_size, void* d_ws, size_t ws_size,
                              hipStream_t stream) {
    const float* x     = (const float*)d_in[0];
    const float* mask  = (const float*)d_in[1];
    const float* Wih0  = (const float*)d_in[2];
    const float* Whh0  = (const float*)d_in[3];
    const float* b_ih0 = (const float*)d_in[4];
    const float* b_hh0 = (const float*)d_in[5];
    const float* Wih1  = (const float*)d_in[6];
    const float* Whh1  = (const float*)d_in[7];
    const float* b_ih1 = (const float*)d_in[8];
    const float* b_hh1 = (const float*)d_in[9];
    const float* W1    = (const float*)d_in[10];
    const float* b1    = (const float*)d_in[11];
    const float* W2    = (const float*)d_in[12];
    const float* b2    = (const float*)d_in[13];

    char* ws = (char*)d_ws;
    size_t off = 0;
    auto take = [&](size_t bytes) { char* p = ws + off; off += (bytes + 255) & ~(size_t)255; return p; };
    float* base    = (float*)take(512 * 512 * 4);
    f16* Whh0h     = (f16*)take(HSZ * 2);
    f16* Wih1h     = (f16*)take(HSZ * 2);
    f16* Whh1h     = (f16*)take(HSZ * 2);
    f16* W1h       = (f16*)take(1048576 * 2);
    f16* W2h       = (f16*)take(524288 * 2);
    f16* h0buf     = (f16*)take(2 * HSZ * 2);
    f16* h1all     = (f16*)take((size_t)129 * HSZ * 2);
    float* pcontrib= (float*)take(128 * 512 * 4);
    f16* A         = (f16*)take(65536 * 2);
    f16* B1        = (f16*)take(65536 * 2);
    float* biasv   = (float*)take(512 * 4);
    int* slots     = (int*)take(4096 * 4);
    if (off > ws_size) return;

    // Optional monotonic h0 slabs (66 MB): enables cached (L2-sharing) h0
    // reads in k_rnn. Deterministic host-side choice based on ws_size.
    const size_t h0all_bytes = (size_t)129 * HSZ * 2;
    bool big = (off + h0all_bytes + 256 <= ws_size);
    f16* h0all = big ? (f16*)take(h0all_bytes) : h0buf;

    k_conv<<<256, 256, 0, stream>>>(x, mask, Wih0, b_ih0, b_hh0, Whh0, Wih1, Whh1,
                                    W1, W2, A, B1, biasv, Whh0h, Wih1h, Whh1h,
                                    W1h, W2h, h1all, slots);
    k_base<<<256, 256, 0, stream>>>(A, B1, biasv, base, h0all);
    if (big)
        k_rnn<true><<<256, 256, 0, stream>>>(h0all, h1all, Whh0h, Wih1h, Whh1h,
                                             base, x, Wih0, b_ih1, b_hh1, slots);
    else
        k_rnn<false><<<256, 256, 0, stream>>>(h0all, h1all, Whh0h, Wih1h, Whh1h,
                                              base, x, Wih0, b_ih1, b_hh1, slots);
    k_phaseB<<<512, 512, 0, stream>>>(h1all, W1h, W2h, b1, b2, x, pcontrib);
    k_fin<<<512, 256, 0, stream>>>(h1all + (size_t)128 * HSZ, pcontrib, (float*)d_out);
}

// Round 8
// 1053.789 us; speedup vs baseline: 5.2079x; 1.0449x over previous
//
#include <hip/hip_runtime.h>

typedef _Float16 f16;
typedef _Float16 f16x8 __attribute__((ext_vector_type(8)));
typedef float    f32x4 __attribute__((ext_vector_type(4)));
typedef unsigned int u32;
typedef u32 u32x4 __attribute__((ext_vector_type(4)));

#define MFMA16(a, b, c) __builtin_amdgcn_mfma_f32_16x16x32_f16((a), (b), (c), 0, 0, 0)

#define HSZ 262144            // 512*512
#define LOGDET_C 235.2482644923962f  // 128*log(2*pi)

// ---- memory access primitives -------------------------------------------
// _n (plain): cacheable; used only on (a) read-only kernel inputs, or
//     (b) monotonic virgin addresses, or (c) verified same-XCD exchange
//     (shared L2 is the coherence point; vmcnt(0) ack precedes flag).
// _s (sc0 sc1): L3 coherence point; proven cross-XCD-safe (rounds 3-7).
__device__ __forceinline__ void ld16_n(u32x4& d, const f16* p) {
    asm volatile("global_load_dwordx4 %0, %1, off" : "=v"(d) : "v"(p));
}
__device__ __forceinline__ void ld16_s(u32x4& d, const f16* p) {
    asm volatile("global_load_dwordx4 %0, %1, off sc0 sc1" : "=v"(d) : "v"(p));
}
__device__ __forceinline__ void st2_n(f16* p, f16 v) {
    u32 u = (u32)__builtin_bit_cast(unsigned short, v);
    asm volatile("global_store_short %0, %1, off" :: "v"(p), "v"(u) : "memory");
}
__device__ __forceinline__ void st2_s(f16* p, f16 v) {
    u32 u = (u32)__builtin_bit_cast(unsigned short, v);
    asm volatile("global_store_short %0, %1, off sc0 sc1" :: "v"(p), "v"(u) : "memory");
}
__device__ __forceinline__ void sti_s(int* p, int v) {
    asm volatile("global_store_dword %0, %1, off sc0 sc1" :: "v"(p), "v"(v) : "memory");
}
__device__ __forceinline__ int ldi_s(const int* p) {
    int v;
    asm volatile("global_load_dword %0, %1, off sc0 sc1\ns_waitcnt vmcnt(0)"
                 : "=v"(v) : "v"(p) : "memory");
    return v;
}
// async global->LDS 16B (per-lane global src, wave-linear LDS dest)
__device__ __forceinline__ void gl16(const f16* g, char* l) {
    __builtin_amdgcn_global_load_lds(
        (const __attribute__((address_space(1))) u32*)g,
        (__attribute__((address_space(3))) u32*)l, 16, 0, 0);
}
// tanh via HW exp2+rcp: tanh(x) = 1 - 2/(exp2(x*2/ln2)+1). |err| ~1e-6.
__device__ __forceinline__ float tanh_fast(float x) {
    float e = __builtin_amdgcn_exp2f(x * 2.8853900817779268f);
    return 1.f - 2.f * __builtin_amdgcn_rcpf(e + 1.f);
}

// ---------------------------------------------------------------------------
// k_conv: conversions + small vectors; init slots=0, xcdtab=-1.
__global__ void k_conv(const float* __restrict__ x, const float* __restrict__ mask,
                       const float* __restrict__ Wih0,
                       const float* __restrict__ b_ih0, const float* __restrict__ b_hh0,
                       const float* __restrict__ Whh0, const float* __restrict__ Wih1,
                       const float* __restrict__ Whh1, const float* __restrict__ W1,
                       const float* __restrict__ W2,
                       f16* __restrict__ A, f16* __restrict__ B1,
                       float* __restrict__ biasv,
                       f16* __restrict__ Whh0h, f16* __restrict__ Wih1h,
                       f16* __restrict__ Whh1h, f16* __restrict__ W1h,
                       f16* __restrict__ W2h, f16* __restrict__ h1all,
                       int* __restrict__ slots, int* __restrict__ xcdtab)
{
    int gid = blockIdx.x * 256 + threadIdx.x;   // 0..65535
    {
        int c = gid >> 7, k = gid & 127;
        A[gid]  = (f16)(x[gid] * mask[k]);
        B1[gid] = (f16)Wih0[c * 257 + 1 + k];
    }
    if (gid < 512) {
        float s = b_ih0[gid] + b_hh0[gid];
        const float* wrow = Wih0 + gid * 257 + 129;
        for (int k = 0; k < 128; k++) s += mask[k] * wrow[k];
        biasv[gid] = s;
    }
    for (int i = gid; i < 262144; i += 65536) {
        Whh0h[i] = (f16)Whh0[i];
        Wih1h[i] = (f16)Wih1[i];
        Whh1h[i] = (f16)Whh1[i];
        h1all[i] = (f16)0.f;      // h1[t=-1]
    }
    for (int i = gid; i < 1048576; i += 65536) W1h[i] = (f16)W1[i];
    for (int i = gid; i < 524288;  i += 65536) W2h[i] = (f16)W2[i];
    if (gid < 4096) { slots[gid] = 0; xcdtab[gid] = -1; }
}

// ---------------------------------------------------------------------------
// k_base: base = A @ B1^T + biasv ; h0 slab0 = tanh(base)
__global__ __launch_bounds__(256) void k_base(const f16* __restrict__ A,
                                              const f16* __restrict__ B1,
                                              const float* __restrict__ biasv,
                                              float* __restrict__ base,
                                              f16* __restrict__ h0s0)
{
    __shared__ float part[4][32][32];
    int tid = threadIdx.x;
    int w = tid >> 6, l = tid & 63;
    int R0 = (blockIdx.x >> 4) * 32, C0 = (blockIdx.x & 15) * 32;
    int lr = l & 15, hi = l >> 4;

    const f16* a0p = A  + (R0 + lr) * 128 + w * 32 + hi * 8;
    const f16* b0p = B1 + (C0 + lr) * 128 + w * 32 + hi * 8;
    f16x8 a0 = *(const f16x8*)(a0p);
    f16x8 a1 = *(const f16x8*)(a0p + 16 * 128);
    f16x8 b0 = *(const f16x8*)(b0p);
    f16x8 b1 = *(const f16x8*)(b0p + 16 * 128);
    f32x4 z = {0.f, 0.f, 0.f, 0.f};
    f32x4 acc00 = MFMA16(a0, b0, z);
    f32x4 acc01 = MFMA16(a0, b1, z);
    f32x4 acc10 = MFMA16(a1, b0, z);
    f32x4 acc11 = MFMA16(a1, b1, z);
#pragma unroll
    for (int r = 0; r < 4; r++) {
        part[w][hi * 4 + r][lr]           = acc00[r];
        part[w][hi * 4 + r][16 + lr]      = acc01[r];
        part[w][16 + hi * 4 + r][lr]      = acc10[r];
        part[w][16 + hi * 4 + r][16 + lr] = acc11[r];
    }
    __syncthreads();
    int rr = tid >> 3, c0 = (tid & 7) * 4;
    int gr = R0 + rr;
#pragma unroll
    for (int cc = 0; cc < 4; cc++) {
        int gc = C0 + c0 + cc;
        float s = part[0][rr][c0 + cc] + part[1][rr][c0 + cc] +
                  part[2][rr][c0 + cc] + part[3][rr][c0 + cc] + biasv[gc];
        base[gr * 512 + gc] = s;
        h0s0[gr * 512 + gc] = (f16)tanh_fast(s);
    }
}

// ---------------------------------------------------------------------------
// Persistent recurrence kernel v4. 256 wgs, 1 wg/CU (94KB LDS pin + high
// VGPR). Weights held ENTIRELY in VGPRs (48 x f16x8 = 192 VGPR/lane; at
// 1 wave/SIMD the budget is 512) -> zero LDS traffic in the loop.
// Exchange protocol (mode chosen per cluster, consistently):
//   - every wg publishes its XCC_ID (sc0 sc1) and runs a BOUNDED poll of its
//     cluster-mates; decision "fast" iff all 16 share one XCD (symmetric ->
//     cluster-consistent). Timeout/mismatch -> slow = exact r7 protocol.
//   - fast: plain stores (ack at shared XCD L2) + plain loads (virgin
//     monotonic addresses; L2 is the intra-XCD coherence point).
//   - flags always sc0 sc1 (proven r3-r7); data-before-flag via vmcnt(0).
#define RNN_PHASES(LD16x, ST2x)                                               \
    for (int p = 0; p < 128; p++) {                                           \
        const f16* H0 = h0all + (size_t)(p & PMASK) * HSZ;                    \
        const f16* H1 = h1all + (size_t)p * HSZ;                              \
        const f16* ap = H0 + (R0 + r_lo + lr) * 512 + hi * 8;                 \
        const f16* bp = H1 + (R0 + r_lo + lr) * 512 + hi * 8;                 \
        float xprev[4];                                                       \
        _Pragma("unroll")                                                     \
        for (int r = 0; r < 4; r++) xprev[r] = x[(outrow + r) * 128 + p];     \
        u32x4 ra0[16], ra1[16];                                               \
        __builtin_amdgcn_sched_barrier(0);                                    \
        _Pragma("unroll")                                                     \
        for (int f = 0; f < 16; f++) LD16x(ra0[f], ap + f * 32);              \
        _Pragma("unroll")                                                     \
        for (int f = 0; f < 16; f++) LD16x(ra1[f], bp + f * 32);              \
        asm volatile("s_waitcnt vmcnt(16)" ::: "memory");                     \
        __builtin_amdgcn_sched_barrier(0);                                    \
        f32x4 acc1 = {0.f, 0.f, 0.f, 0.f}, acc0n = acc1;                      \
        _Pragma("unroll")                                                     \
        for (int f = 0; f < 16; f++) {                                        \
            f16x8 a = __builtin_bit_cast(f16x8, ra0[f]);                      \
            acc1  = MFMA16(a, bW1[f], acc1);                                  \
            acc0n = MFMA16(a, bW0[f], acc0n);                                 \
        }                                                                     \
        asm volatile("s_waitcnt vmcnt(0)" ::: "memory");                      \
        __builtin_amdgcn_sched_barrier(0);                                    \
        _Pragma("unroll")                                                     \
        for (int f = 0; f < 16; f++) {                                        \
            f16x8 a = __builtin_bit_cast(f16x8, ra1[f]);                      \
            acc1 = MFMA16(a, bW2[f], acc1);                                   \
        }                                                                     \
        f16* H1o = h1all + (size_t)(p + 1) * HSZ;                             \
        f16* H0o = h0all + (size_t)((p + 1) & PMASK) * HSZ;                   \
        _Pragma("unroll")                                                     \
        for (int r = 0; r < 4; r++) {                                         \
            f16 v1 = (f16)tanh_fast(acc1[r] + bsum);                          \
            f16 v0 = (f16)tanh_fast(acc0n[r] + basef[r] + xprev[r] * w0);     \
            ST2x(H1o + (outrow + r) * 512 + outcolg, v1);                     \
            ST2x(H0o + (outrow + r) * 512 + outcolg, v0);                     \
        }                                                                     \
        if (p < 127) {                                                        \
            asm volatile("s_waitcnt vmcnt(0)" ::: "memory");                  \
            __syncthreads();                                                  \
            if (w == 0) {                                                     \
                int target = p + 1;                                           \
                if (l == 0) sti_s(myslot, target);                            \
                int v;                                                        \
                do { v = (l < 16) ? ldi_s(peerslot) : target; }               \
                while (!__all(v >= target));                                  \
            }                                                                 \
            __syncthreads();                                                  \
        }                                                                     \
    }

template<bool H0F>
__global__ __launch_bounds__(256, 1) void k_rnn(
    f16* __restrict__ h0all, f16* __restrict__ h1all,
    const f16* __restrict__ Whh0h, const f16* __restrict__ Wih1h,
    const f16* __restrict__ Whh1h,
    const float* __restrict__ base, const float* __restrict__ x,
    const float* __restrict__ Wih0, const float* __restrict__ b_ih1,
    const float* __restrict__ b_hh1, int* __restrict__ slots,
    int* __restrict__ xcdtab)
{
    constexpr int PMASK = H0F ? 255 : 1;
    __shared__ int s_fast;
    __shared__ volatile int pin[23552];   // 94KB: pins 1 wg/CU
    int tid = threadIdx.x;
    int w = tid >> 6, l = tid & 63;
    int bid = blockIdx.x;
    int sub = (bid >> 3) & 1, cj = bid >> 4;
    int cluster = (bid & 7) * 2 + sub;       // cluster-mates share bid&7
    int R0 = cluster * 32, C0 = cj * 32;
    pin[tid] = 0;                            // touch -> LDS kept

    int xcdreg;
    asm("s_getreg_b32 %0, hwreg(20, 0, 32)" : "=s"(xcdreg));  // HW_REG_XCC_ID
    int my_xcd = xcdreg & 7;
    if (H0F && tid == 0) sti_s(xcdtab + (cluster * 16 + cj) * 16, my_xcd);

    int lr = l & 15, hi = l >> 4;
    int r_lo = (w >> 1) * 16, c_lo = (w & 1) * 16;
    int outrow = R0 + r_lo + hi * 4;
    int outcolg = C0 + c_lo + lr;

    // ---- weight B-fragments into registers (loaded once, plain cacheable)
    f16x8 bW0[16], bW1[16], bW2[16];
    {
        const f16* w0p = Whh0h + (size_t)outcolg * 512 + hi * 8;
        const f16* w1p = Wih1h + (size_t)outcolg * 512 + hi * 8;
        const f16* w2p = Whh1h + (size_t)outcolg * 512 + hi * 8;
#pragma unroll
        for (int f = 0; f < 16; f++) {
            bW0[f] = *(const f16x8*)(w0p + f * 32);
            bW1[f] = *(const f16x8*)(w1p + f * 32);
            bW2[f] = *(const f16x8*)(w2p + f * 32);
        }
    }

    float basef[4];
#pragma unroll
    for (int r = 0; r < 4; r++) basef[r] = base[(outrow + r) * 512 + outcolg];
    float w0 = Wih0[outcolg * 257];
    float bsum = b_ih1[outcolg] + b_hh1[outcolg];

    int* myslot = slots + (cluster * 16 + cj) * 16;
    int* peerslot = slots + (cluster * 16 + (l & 15)) * 16;

    // ---- bounded cluster-locality verification (deadlock-impossible)
    bool fast = false;
    if constexpr (H0F) {
        if (w == 0) {
            int ok = 0;
            for (int it = 0; it < 512; ++it) {
                int v = (l < 16) ? ldi_s(xcdtab + (cluster * 16 + l) * 16)
                                 : my_xcd;
                if (__all(l >= 16 || v != -1)) {      // all published
                    ok = __all(l >= 16 || v == my_xcd);
                    break;
                }
            }
            if (l == 0) s_fast = ok;
        }
        __syncthreads();
        fast = (s_fast != 0);
    } else {
        if (tid == 0) s_fast = 0;
        __syncthreads();
    }

    if (fast) {
        RNN_PHASES(ld16_n, st2_n)
    } else {
        RNN_PHASES(ld16_s, st2_s)
    }
}

// ---------------------------------------------------------------------------
// Phase B v3 (unchanged from round 5)
__global__ __launch_bounds__(512, 2) void k_phaseB(const f16* __restrict__ h1all,
                                                   const f16* __restrict__ W1h,
                                                   const f16* __restrict__ W2h,
                                                   const float* __restrict__ b1v,
                                                   const float* __restrict__ b2,
                                                   const float* __restrict__ x,
                                                   float* __restrict__ pcontrib)
{
    __shared__ __align__(16) char Wl[108544];
    const int OFF_W2 = 65536, OFF_HID = 98304;

    int tid = threadIdx.x;
    int wv = tid >> 6, l = tid & 63;
    int lr = l & 15, hi = l >> 4;
    int M0 = blockIdx.x * 128;

    const f16* Hrow = h1all + HSZ + (size_t)(M0 + wv * 16 + lr) * 512;
    f16x8 afrag[16];
#pragma unroll
    for (int ks = 0; ks < 16; ks++)
        afrag[ks] = *(const f16x8*)(Hrow + ks * 32 + hi * 8);

    f32x4 mc[16] = {};

    {
#pragma unroll
        for (int it = 0; it < 4; it++) {
            int idx = it * 512 + tid;
            gl16(W1h + (size_t)(idx & 31) * 512 + (idx >> 5) * 8,
                 Wl + idx * 16);
        }
#pragma unroll
        for (int it = 0; it < 2; it++) {
            int idx = it * 512 + tid;
            gl16(W2h + (size_t)(idx & 255) * 2048 + (idx >> 8) * 8,
                 Wl + OFF_W2 + idx * 16);
        }
    }

    for (int c = 0; c < 64; c++) {
        int p = c & 1;
        __syncthreads();

        if (c + 1 < 64) {
            const int nc = (c + 1) * 32, q = p ^ 1;
#pragma unroll
            for (int it = 0; it < 4; it++) {
                int idx = it * 512 + tid;
                gl16(W1h + (size_t)(nc + (idx & 31)) * 512 + (idx >> 5) * 8,
                     Wl + q * 32768 + idx * 16);
            }
#pragma unroll
            for (int it = 0; it < 2; it++) {
                int idx = it * 512 + tid;
                gl16(W2h + (size_t)(idx & 255) * 2048 + nc + (idx >> 8) * 8,
                     Wl + OFF_W2 + q * 16384 + idx * 16);
            }
        }

        {
            f32x4 s3a = {0.f, 0.f, 0.f, 0.f}, s3b = s3a;
#pragma unroll
            for (int ks = 0; ks < 16; ks++) {
                f16x8 wb0 = *(const f16x8*)(Wl + p * 32768 +
                                            ((ks * 4 + hi) * 32 + lr) * 16);
                f16x8 wb1 = *(const f16x8*)(Wl + p * 32768 +
                                            ((ks * 4 + hi) * 32 + 16 + lr) * 16);
                s3a = MFMA16(afrag[ks], wb0, s3a);
                s3b = MFMA16(afrag[ks], wb1, s3b);
            }
            float bb0 = b1v[c * 32 + lr];
            float bb1 = b1v[c * 32 + 16 + lr];
#pragma unroll
            for (int r = 0; r < 4; r++) {
                int lrow = wv * 16 + hi * 4 + r;
                *(f16*)(Wl + OFF_HID + (lrow * 40 + lr) * 2) =
                    (f16)fmaxf(s3a[r] + bb0, 0.f);
                *(f16*)(Wl + OFF_HID + (lrow * 40 + 16 + lr) * 2) =
                    (f16)fmaxf(s3b[r] + bb1, 0.f);
            }
        }
        __syncthreads();

        {
            f16x8 a = *(const f16x8*)(Wl + OFF_HID +
                                      ((wv * 16 + lr) * 40 + hi * 8) * 2);
#pragma unroll
            for (int cf = 0; cf < 16; cf++) {
                f16x8 b = *(const f16x8*)(Wl + OFF_W2 + p * 16384 +
                                          (hi * 256 + cf * 16 + lr) * 16);
                mc[cf] = MFMA16(a, b, mc[cf]);
            }
        }
    }

    float quad[4] = {}, ls[4] = {}, xt[4];
#pragma unroll
    for (int r = 0; r < 4; r++) {
        int m = M0 + wv * 16 + hi * 4 + r;
        xt[r] = x[(m & 511) * 128 + (m >> 9)];
    }
#pragma unroll
    for (int cf = 0; cf < 8; cf++) {
        int cc = cf * 16 + lr;
        float bm = b2[cc], bc = b2[128 + cc];
#pragma unroll
        for (int r = 0; r < 4; r++) {
            float mean = mc[cf][r] + bm;
            float cov  = mc[cf + 8][r] + bc;
            float sp = log1pf(expf(-fabsf(cov))) + fmaxf(cov, 0.f);
            float d = xt[r] - mean;
            quad[r] += d * d * sp;
            ls[r] += logf(sp);
        }
    }
#pragma unroll
    for (int mm = 1; mm < 16; mm <<= 1)
#pragma unroll
        for (int r = 0; r < 4; r++) {
            quad[r] += __shfl_xor(quad[r], mm, 64);
            ls[r]   += __shfl_xor(ls[r], mm, 64);
        }
    if (lr == 0) {
#pragma unroll
        for (int r = 0; r < 4; r++) {
            int m = M0 + wv * 16 + hi * 4 + r;
            pcontrib[m] = -0.5f * (LOGDET_C + quad[r]) - 0.5f * ls[r];
        }
    }
}

// ---------------------------------------------------------------------------
__global__ void k_fin(const f16* __restrict__ h1last,
                      const float* __restrict__ pcontrib, float* __restrict__ out)
{
    int gid = blockIdx.x * 256 + threadIdx.x;
    for (int i = gid; i < HSZ; i += 131072) out[i] = (float)h1last[i];
    if (gid < 512) {
        float s = 0.f;
        for (int tt = 0; tt < 128; tt++) s += pcontrib[tt * 512 + gid];
        out[HSZ + gid] = s;
    }
}

// ---------------------------------------------------------------------------
extern "C" void kernel_launch(void* const* d_in, const int* in_sizes, int n_in,
                              void* d_out, int out_size, void* d_ws, size_t ws_size,
                              hipStream_t stream) {
    const float* x     = (const float*)d_in[0];
    const float* mask  = (const float*)d_in[1];
    const float* Wih0  = (const float*)d_in[2];
    const float* Whh0  = (const float*)d_in[3];
    const float* b_ih0 = (const float*)d_in[4];
    const float* b_hh0 = (const float*)d_in[5];
    const float* Wih1  = (const float*)d_in[6];
    const float* Whh1  = (const float*)d_in[7];
    const float* b_ih1 = (const float*)d_in[8];
    const float* b_hh1 = (const float*)d_in[9];
    const float* W1    = (const float*)d_in[10];
    const float* b1    = (const float*)d_in[11];
    const float* W2    = (const float*)d_in[12];
    const float* b2    = (const float*)d_in[13];

    char* ws = (char*)d_ws;
    size_t off = 0;
    auto take = [&](size_t bytes) { char* p = ws + off; off += (bytes + 255) & ~(size_t)255; return p; };
    float* base    = (float*)take(512 * 512 * 4);
    f16* Whh0h     = (f16*)take(HSZ * 2);
    f16* Wih1h     = (f16*)take(HSZ * 2);
    f16* Whh1h     = (f16*)take(HSZ * 2);
    f16* W1h       = (f16*)take(1048576 * 2);
    f16* W2h       = (f16*)take(524288 * 2);
    f16* h0buf     = (f16*)take(2 * HSZ * 2);
    f16* h1all     = (f16*)take((size_t)129 * HSZ * 2);
    float* pcontrib= (float*)take(128 * 512 * 4);
    f16* A         = (f16*)take(65536 * 2);
    f16* B1        = (f16*)take(65536 * 2);
    float* biasv   = (float*)take(512 * 4);
    int* slots     = (int*)take(4096 * 4);
    int* xcdtab    = (int*)take(4096 * 4);
    if (off > ws_size) return;

    // Optional monotonic h0 slabs (66 MB): enables cached/virgin h0 reads.
    const size_t h0all_bytes = (size_t)129 * HSZ * 2;
    bool big = (off + h0all_bytes + 256 <= ws_size);
    f16* h0all = big ? (f16*)take(h0all_bytes) : h0buf;

    k_conv<<<256, 256, 0, stream>>>(x, mask, Wih0, b_ih0, b_hh0, Whh0, Wih1, Whh1,
                                    W1, W2, A, B1, biasv, Whh0h, Wih1h, Whh1h,
                                    W1h, W2h, h1all, slots, xcdtab);
    k_base<<<256, 256, 0, stream>>>(A, B1, biasv, base, h0all);
    if (big)
        k_rnn<true><<<256, 256, 0, stream>>>(h0all, h1all, Whh0h, Wih1h, Whh1h,
                                             base, x, Wih0, b_ih1, b_hh1, slots,
                                             xcdtab);
    else
        k_rnn<false><<<256, 256, 0, stream>>>(h0all, h1all, Whh0h, Wih1h, Whh1h,
                                              base, x, Wih0, b_ih1, b_hh1, slots,
                                              xcdtab);
    k_phaseB<<<512, 512, 0, stream>>>(h1all, W1h, W2h, b1, b2, x, pcontrib);
    k_fin<<<512, 256, 0, stream>>>(h1all + (size_t)128 * HSZ, pcontrib, (float*)d_out);
}

// Round 9
// 1006.465 us; speedup vs baseline: 5.4528x; 1.0470x over previous
//
#include <hip/hip_runtime.h>

typedef _Float16 f16;
typedef _Float16 f16x8 __attribute__((ext_vector_type(8)));
typedef float    f32x4 __attribute__((ext_vector_type(4)));
typedef unsigned int u32;
typedef u32 u32x4 __attribute__((ext_vector_type(4)));

#define MFMA16(a, b, c) __builtin_amdgcn_mfma_f32_16x16x32_f16((a), (b), (c), 0, 0, 0)

#define HSZ 262144            // 512*512
#define LOGDET_C 235.2482644923962f  // 128*log(2*pi)

// ---- memory access primitives -------------------------------------------
// _n (plain): cacheable; used only on read-only inputs, virgin monotonic
//     addresses, or verified same-XCD exchange (shared L2 coherence point).
// _s (sc0 sc1): L3 coherence point; proven cross-XCD-safe (rounds 3-8).
__device__ __forceinline__ void ld16_n(u32x4& d, const f16* p) {
    asm volatile("global_load_dwordx4 %0, %1, off" : "=v"(d) : "v"(p));
}
__device__ __forceinline__ void ld16_s(u32x4& d, const f16* p) {
    asm volatile("global_load_dwordx4 %0, %1, off sc0 sc1" : "=v"(d) : "v"(p));
}
__device__ __forceinline__ void st2_n(f16* p, f16 v) {
    u32 u = (u32)__builtin_bit_cast(unsigned short, v);
    asm volatile("global_store_short %0, %1, off" :: "v"(p), "v"(u) : "memory");
}
__device__ __forceinline__ void st2_s(f16* p, f16 v) {
    u32 u = (u32)__builtin_bit_cast(unsigned short, v);
    asm volatile("global_store_short %0, %1, off sc0 sc1" :: "v"(p), "v"(u) : "memory");
}
__device__ __forceinline__ void sti_s(int* p, int v) {
    asm volatile("global_store_dword %0, %1, off sc0 sc1" :: "v"(p), "v"(v) : "memory");
}
__device__ __forceinline__ int ldi_s(const int* p) {
    int v;
    asm volatile("global_load_dword %0, %1, off sc0 sc1\ns_waitcnt vmcnt(0)"
                 : "=v"(v) : "v"(p) : "memory");
    return v;
}
// async global->LDS 16B (per-lane global src, wave-linear LDS dest)
__device__ __forceinline__ void gl16(const f16* g, char* l) {
    __builtin_amdgcn_global_load_lds(
        (const __attribute__((address_space(1))) u32*)g,
        (__attribute__((address_space(3))) u32*)l, 16, 0, 0);
}
// tanh via HW exp2+rcp: tanh(x) = 1 - 2/(exp2(x*2/ln2)+1). |err| ~1e-6.
__device__ __forceinline__ float tanh_fast(float x) {
    float e = __builtin_amdgcn_exp2f(x * 2.8853900817779268f);
    return 1.f - 2.f * __builtin_amdgcn_rcpf(e + 1.f);
}

// ---------------------------------------------------------------------------
// k_conv: conversions + small vectors; init slots=0 (32K ints), xcdtab=-1.
__global__ void k_conv(const float* __restrict__ x, const float* __restrict__ mask,
                       const float* __restrict__ Wih0,
                       const float* __restrict__ b_ih0, const float* __restrict__ b_hh0,
                       const float* __restrict__ Whh0, const float* __restrict__ Wih1,
                       const float* __restrict__ Whh1, const float* __restrict__ W1,
                       const float* __restrict__ W2,
                       f16* __restrict__ A, f16* __restrict__ B1,
                       float* __restrict__ biasv,
                       f16* __restrict__ Whh0h, f16* __restrict__ Wih1h,
                       f16* __restrict__ Whh1h, f16* __restrict__ W1h,
                       f16* __restrict__ W2h, f16* __restrict__ h1all,
                       int* __restrict__ slots, int* __restrict__ xcdtab)
{
    int gid = blockIdx.x * 256 + threadIdx.x;   // 0..65535
    {
        int c = gid >> 7, k = gid & 127;
        A[gid]  = (f16)(x[gid] * mask[k]);
        B1[gid] = (f16)Wih0[c * 257 + 1 + k];
    }
    if (gid < 512) {
        float s = b_ih0[gid] + b_hh0[gid];
        const float* wrow = Wih0 + gid * 257 + 129;
        for (int k = 0; k < 128; k++) s += mask[k] * wrow[k];
        biasv[gid] = s;
    }
    for (int i = gid; i < 262144; i += 65536) {
        Whh0h[i] = (f16)Whh0[i];
        Wih1h[i] = (f16)Wih1[i];
        Whh1h[i] = (f16)Whh1[i];
        h1all[i] = (f16)0.f;      // h1[t=-1]
    }
    for (int i = gid; i < 1048576; i += 65536) W1h[i] = (f16)W1[i];
    for (int i = gid; i < 524288;  i += 65536) W2h[i] = (f16)W2[i];
    if (gid < 32768) slots[gid] = 0;
    if (gid < 4096)  xcdtab[gid] = -1;
}

// ---------------------------------------------------------------------------
// k_base: base = A @ B1^T + biasv ; h0 slab0 = tanh(base)
__global__ __launch_bounds__(256) void k_base(const f16* __restrict__ A,
                                              const f16* __restrict__ B1,
                                              const float* __restrict__ biasv,
                                              float* __restrict__ base,
                                              f16* __restrict__ h0s0)
{
    __shared__ float part[4][32][32];
    int tid = threadIdx.x;
    int w = tid >> 6, l = tid & 63;
    int R0 = (blockIdx.x >> 4) * 32, C0 = (blockIdx.x & 15) * 32;
    int lr = l & 15, hi = l >> 4;

    const f16* a0p = A  + (R0 + lr) * 128 + w * 32 + hi * 8;
    const f16* b0p = B1 + (C0 + lr) * 128 + w * 32 + hi * 8;
    f16x8 a0 = *(const f16x8*)(a0p);
    f16x8 a1 = *(const f16x8*)(a0p + 16 * 128);
    f16x8 b0 = *(const f16x8*)(b0p);
    f16x8 b1 = *(const f16x8*)(b0p + 16 * 128);
    f32x4 z = {0.f, 0.f, 0.f, 0.f};
    f32x4 acc00 = MFMA16(a0, b0, z);
    f32x4 acc01 = MFMA16(a0, b1, z);
    f32x4 acc10 = MFMA16(a1, b0, z);
    f32x4 acc11 = MFMA16(a1, b1, z);
#pragma unroll
    for (int r = 0; r < 4; r++) {
        part[w][hi * 4 + r][lr]           = acc00[r];
        part[w][hi * 4 + r][16 + lr]      = acc01[r];
        part[w][16 + hi * 4 + r][lr]      = acc10[r];
        part[w][16 + hi * 4 + r][16 + lr] = acc11[r];
    }
    __syncthreads();
    int rr = tid >> 3, c0 = (tid & 7) * 4;
    int gr = R0 + rr;
#pragma unroll
    for (int cc = 0; cc < 4; cc++) {
        int gc = C0 + c0 + cc;
        float s = part[0][rr][c0 + cc] + part[1][rr][c0 + cc] +
                  part[2][rr][c0 + cc] + part[3][rr][c0 + cc] + biasv[gc];
        base[gr * 512 + gc] = s;
        h0s0[gr * 512 + gc] = (f16)tanh_fast(s);
    }
}

// ---------------------------------------------------------------------------
// Persistent recurrence kernel v5: per-WAVE dataflow signals, zero
// __syncthreads in the loop, h0-critical-path-first schedule.
//   slotB[wave]=p+1 : this wave's h0[p+1] columns are stored (drained)
//   slotA[wave]=p+1 : this wave's h1[p]   columns are stored (drained)
// Phase p: pollB>=p -> load h0[p] -> M2 -> tanh -> store h0[p+1] -> sigB
//          pollA>=p -> load h1[p-1] -> M3+M1 -> tanh -> store h1[p] -> sigA
// Flags always sc0 sc1 (proven). Data: plain in verified same-XCD clusters
// (virgin monotonic slabs / shared-L2 coherence), else sc0 sc1.
// Skew-safety w/o barriers: slab p+1 writes happen only after observing
// B(p) from ALL peer waves, which post-dates their slab p-1 reads.
#define RNN_PHASES(LD16x, ST2x)                                               \
    for (int p = 0; p < 128; p++) {                                           \
        const f16* H0 = h0all + (size_t)(p & PMASK) * HSZ;                    \
        const f16* H1 = h1all + (size_t)p * HSZ;                              \
        const f16* ap = H0 + (R0 + r_lo + lr) * 512 + hi * 8;                 \
        const f16* bp = H1 + (R0 + r_lo + lr) * 512 + hi * 8;                 \
        f16* H1o = h1all + (size_t)(p + 1) * HSZ;                             \
        f16* H0o = h0all + (size_t)((p + 1) & PMASK) * HSZ;                   \
        float xprev[4];                                                       \
        _Pragma("unroll")                                                     \
        for (int r = 0; r < 4; r++) xprev[r] = x[(outrow + r) * 128 + p];     \
        if (p) { int v; do { v = ldi_s(pollB); } while (!__all(v >= p)); }    \
        u32x4 ra0[16], ra1[16];                                               \
        __builtin_amdgcn_sched_barrier(0);                                    \
        _Pragma("unroll")                                                     \
        for (int f = 0; f < 16; f++) LD16x(ra0[f], ap + f * 32);              \
        asm volatile("s_waitcnt vmcnt(0)" ::: "memory");                      \
        __builtin_amdgcn_sched_barrier(0);                                    \
        f32x4 z4 = {0.f, 0.f, 0.f, 0.f};                                      \
        f32x4 a0a = z4, a0b = z4;                                             \
        _Pragma("unroll")                                                     \
        for (int f = 0; f < 16; f += 2) {                                     \
            a0a = MFMA16(__builtin_bit_cast(f16x8, ra0[f]), bW0[f], a0a);     \
            a0b = MFMA16(__builtin_bit_cast(f16x8, ra0[f+1]), bW0[f+1], a0b); \
        }                                                                     \
        f32x4 acc0 = a0a + a0b;                                               \
        _Pragma("unroll")                                                     \
        for (int r = 0; r < 4; r++) {                                         \
            f16 v0 = (f16)tanh_fast(acc0[r] + basef[r] + xprev[r] * w0);      \
            ST2x(H0o + (outrow + r) * 512 + outcolg, v0);                     \
        }                                                                     \
        asm volatile("s_waitcnt vmcnt(0)" ::: "memory");                      \
        if (l == 0) sti_s(myB, p + 1);                                        \
        if (p) { int v; do { v = ldi_s(pollA); } while (!__all(v >= p)); }    \
        __builtin_amdgcn_sched_barrier(0);                                    \
        _Pragma("unroll")                                                     \
        for (int f = 0; f < 16; f++) LD16x(ra1[f], bp + f * 32);              \
        asm volatile("s_waitcnt vmcnt(0)" ::: "memory");                      \
        __builtin_amdgcn_sched_barrier(0);                                    \
        f32x4 a1a = z4, a1b = z4;                                             \
        _Pragma("unroll")                                                     \
        for (int f = 0; f < 16; f += 2) {                                     \
            a1a = MFMA16(__builtin_bit_cast(f16x8, ra1[f]), bW2[f], a1a);     \
            a1b = MFMA16(__builtin_bit_cast(f16x8, ra1[f+1]), bW2[f+1], a1b); \
            a1a = MFMA16(__builtin_bit_cast(f16x8, ra0[f]), bW1[f], a1a);     \
            a1b = MFMA16(__builtin_bit_cast(f16x8, ra0[f+1]), bW1[f+1], a1b); \
        }                                                                     \
        f32x4 acc1 = a1a + a1b;                                               \
        _Pragma("unroll")                                                     \
        for (int r = 0; r < 4; r++) {                                         \
            f16 v1 = (f16)tanh_fast(acc1[r] + bsum);                          \
            ST2x(H1o + (outrow + r) * 512 + outcolg, v1);                     \
        }                                                                     \
        asm volatile("s_waitcnt vmcnt(0)" ::: "memory");                      \
        if (l == 0) sti_s(myA, p + 1);                                        \
    }

template<bool H0F>
__global__ __launch_bounds__(256, 1) void k_rnn(
    f16* __restrict__ h0all, f16* __restrict__ h1all,
    const f16* __restrict__ Whh0h, const f16* __restrict__ Wih1h,
    const f16* __restrict__ Whh1h,
    const float* __restrict__ base, const float* __restrict__ x,
    const float* __restrict__ Wih0, const float* __restrict__ b_ih1,
    const float* __restrict__ b_hh1, int* __restrict__ slots,
    int* __restrict__ xcdtab)
{
    constexpr int PMASK = H0F ? 255 : 1;
    __shared__ int s_fast;
    __shared__ volatile int pin[23552];   // 94KB: pins 1 wg/CU
    int tid = threadIdx.x;
    int w = tid >> 6, l = tid & 63;
    int bid = blockIdx.x;
    int sub = (bid >> 3) & 1, cj = bid >> 4;
    int cluster = (bid & 7) * 2 + sub;       // cluster-mates share bid&7
    int R0 = cluster * 32, C0 = cj * 32;
    pin[tid] = 0;                            // touch -> LDS kept

    int xcdreg;
    asm("s_getreg_b32 %0, hwreg(20, 0, 32)" : "=s"(xcdreg));  // HW_REG_XCC_ID
    int my_xcd = xcdreg & 7;
    if (H0F && tid == 0) sti_s(xcdtab + (cluster * 16 + cj) * 16, my_xcd);

    int lr = l & 15, hi = l >> 4;
    int r_lo = (w >> 1) * 16, c_lo = (w & 1) * 16;
    int outrow = R0 + r_lo + hi * 4;
    int outcolg = C0 + c_lo + lr;

    // ---- weight B-fragments into registers (loaded once, plain cacheable)
    f16x8 bW0[16], bW1[16], bW2[16];
    {
        const f16* w0p = Whh0h + (size_t)outcolg * 512 + hi * 8;
        const f16* w1p = Wih1h + (size_t)outcolg * 512 + hi * 8;
        const f16* w2p = Whh1h + (size_t)outcolg * 512 + hi * 8;
#pragma unroll
        for (int f = 0; f < 16; f++) {
            bW0[f] = *(const f16x8*)(w0p + f * 32);
            bW1[f] = *(const f16x8*)(w1p + f * 32);
            bW2[f] = *(const f16x8*)(w2p + f * 32);
        }
    }

    float basef[4];
#pragma unroll
    for (int r = 0; r < 4; r++) basef[r] = base[(outrow + r) * 512 + outcolg];
    float w0 = Wih0[outcolg * 257];
    float bsum = b_ih1[outcolg] + b_hh1[outcolg];

    // ---- per-wave slot pointers (A = slots[0..16K), B = slots[16K..32K))
    int* slotA = slots;
    int* slotB = slots + 16384;
    int wslot = cj * 4 + w;                   // 0..63 within cluster
    int* myA = slotA + (cluster * 64 + wslot) * 16;
    int* myB = slotB + (cluster * 64 + wslot) * 16;
    const int* pollA = slotA + (cluster * 64 + l) * 16;   // lane l -> slot l
    const int* pollB = slotB + (cluster * 64 + l) * 16;

    // ---- cluster XCD-locality verification (consistent, no timeout path:
    //      publishes are guaranteed by 1wg/CU co-residency; polling primitive
    //      is the 6-round-proven sc0sc1 load)
    bool fast = false;
    if constexpr (H0F) {
        if (w == 0) {
            int v;
            do { v = (l < 16) ? ldi_s(xcdtab + (cluster * 16 + l) * 16) : 0; }
            while (__any(l < 16 && v == -1));
            int f = __all(l >= 16 || v == my_xcd);
            if (l == 0) s_fast = f;
        }
        __syncthreads();
        fast = (s_fast != 0);
    } else {
        if (tid == 0) s_fast = 0;
        __syncthreads();
    }

    if (H0F && fast) {
        RNN_PHASES(ld16_n, st2_n)      // same-XCD: shared L2 coherence
    } else if (H0F) {
        RNN_PHASES(ld16_n, st2_s)      // virgin slabs: plain reads, L3 writes
    } else {
        RNN_PHASES(ld16_s, st2_s)      // 2-slab ring: full L3 coherence
    }
}

// ---------------------------------------------------------------------------
// Phase B v3 (unchanged from round 5)
__global__ __launch_bounds__(512, 2) void k_phaseB(const f16* __restrict__ h1all,
                                                   const f16* __restrict__ W1h,
                                                   const f16* __restrict__ W2h,
                                                   const float* __restrict__ b1v,
                                                   const float* __restrict__ b2,
                                                   const float* __restrict__ x,
                                                   float* __restrict__ pcontrib)
{
    __shared__ __align__(16) char Wl[108544];
    const int OFF_W2 = 65536, OFF_HID = 98304;

    int tid = threadIdx.x;
    int wv = tid >> 6, l = tid & 63;
    int lr = l & 15, hi = l >> 4;
    int M0 = blockIdx.x * 128;

    const f16* Hrow = h1all + HSZ + (size_t)(M0 + wv * 16 + lr) * 512;
    f16x8 afrag[16];
#pragma unroll
    for (int ks = 0; ks < 16; ks++)
        afrag[ks] = *(const f16x8*)(Hrow + ks * 32 + hi * 8);

    f32x4 mc[16] = {};

    {
#pragma unroll
        for (int it = 0; it < 4; it++) {
            int idx = it * 512 + tid;
            gl16(W1h + (size_t)(idx & 31) * 512 + (idx >> 5) * 8,
                 Wl + idx * 16);
        }
#pragma unroll
        for (int it = 0; it < 2; it++) {
            int idx = it * 512 + tid;
            gl16(W2h + (size_t)(idx & 255) * 2048 + (idx >> 8) * 8,
                 Wl + OFF_W2 + idx * 16);
        }
    }

    for (int c = 0; c < 64; c++) {
        int p = c & 1;
        __syncthreads();

        if (c + 1 < 64) {
            const int nc = (c + 1) * 32, q = p ^ 1;
#pragma unroll
            for (int it = 0; it < 4; it++) {
                int idx = it * 512 + tid;
                gl16(W1h + (size_t)(nc + (idx & 31)) * 512 + (idx >> 5) * 8,
                     Wl + q * 32768 + idx * 16);
            }
#pragma unroll
            for (int it = 0; it < 2; it++) {
                int idx = it * 512 + tid;
                gl16(W2h + (size_t)(idx & 255) * 2048 + nc + (idx >> 8) * 8,
                     Wl + OFF_W2 + q * 16384 + idx * 16);
            }
        }

        {
            f32x4 s3a = {0.f, 0.f, 0.f, 0.f}, s3b = s3a;
#pragma unroll
            for (int ks = 0; ks < 16; ks++) {
                f16x8 wb0 = *(const f16x8*)(Wl + p * 32768 +
                                            ((ks * 4 + hi) * 32 + lr) * 16);
                f16x8 wb1 = *(const f16x8*)(Wl + p * 32768 +
                                            ((ks * 4 + hi) * 32 + 16 + lr) * 16);
                s3a = MFMA16(afrag[ks], wb0, s3a);
                s3b = MFMA16(afrag[ks], wb1, s3b);
            }
            float bb0 = b1v[c * 32 + lr];
            float bb1 = b1v[c * 32 + 16 + lr];
#pragma unroll
            for (int r = 0; r < 4; r++) {
                int lrow = wv * 16 + hi * 4 + r;
                *(f16*)(Wl + OFF_HID + (lrow * 40 + lr) * 2) =
                    (f16)fmaxf(s3a[r] + bb0, 0.f);
                *(f16*)(Wl + OFF_HID + (lrow * 40 + 16 + lr) * 2) =
                    (f16)fmaxf(s3b[r] + bb1, 0.f);
            }
        }
        __syncthreads();

        {
            f16x8 a = *(const f16x8*)(Wl + OFF_HID +
                                      ((wv * 16 + lr) * 40 + hi * 8) * 2);
#pragma unroll
            for (int cf = 0; cf < 16; cf++) {
                f16x8 b = *(const f16x8*)(Wl + OFF_W2 + p * 16384 +
                                          (hi * 256 + cf * 16 + lr) * 16);
                mc[cf] = MFMA16(a, b, mc[cf]);
            }
        }
    }

    float quad[4] = {}, ls[4] = {}, xt[4];
#pragma unroll
    for (int r = 0; r < 4; r++) {
        int m = M0 + wv * 16 + hi * 4 + r;
        xt[r] = x[(m & 511) * 128 + (m >> 9)];
    }
#pragma unroll
    for (int cf = 0; cf < 8; cf++) {
        int cc = cf * 16 + lr;
        float bm = b2[cc], bc = b2[128 + cc];
#pragma unroll
        for (int r = 0; r < 4; r++) {
            float mean = mc[cf][r] + bm;
            float cov  = mc[cf + 8][r] + bc;
            float sp = log1pf(expf(-fabsf(cov))) + fmaxf(cov, 0.f);
            float d = xt[r] - mean;
            quad[r] += d * d * sp;
            ls[r] += logf(sp);
        }
    }
#pragma unroll
    for (int mm = 1; mm < 16; mm <<= 1)
#pragma unroll
        for (int r = 0; r < 4; r++) {
            quad[r] += __shfl_xor(quad[r], mm, 64);
            ls[r]   += __shfl_xor(ls[r], mm, 64);
        }
    if (lr == 0) {
#pragma unroll
        for (int r = 0; r < 4; r++) {
            int m = M0 + wv * 16 + hi * 4 + r;
            pcontrib[m] = -0.5f * (LOGDET_C + quad[r]) - 0.5f * ls[r];
        }
    }
}

// ---------------------------------------------------------------------------
__global__ void k_fin(const f16* __restrict__ h1last,
                      const float* __restrict__ pcontrib, float* __restrict__ out)
{
    int gid = blockIdx.x * 256 + threadIdx.x;
    for (int i = gid; i < HSZ; i += 131072) out[i] = (float)h1last[i];
    if (gid < 512) {
        float s = 0.f;
        for (int tt = 0; tt < 128; tt++) s += pcontrib[tt * 512 + gid];
        out[HSZ + gid] = s;
    }
}

// ---------------------------------------------------------------------------
extern "C" void kernel_launch(void* const* d_in, const int* in_sizes, int n_in,
                              void* d_out, int out_size, void* d_ws, size_t ws_size,
                              hipStream_t stream) {
    const float* x     = (const float*)d_in[0];
    const float* mask  = (const float*)d_in[1];
    const float* Wih0  = (const float*)d_in[2];
    const float* Whh0  = (const float*)d_in[3];
    const float* b_ih0 = (const float*)d_in[4];
    const float* b_hh0 = (const float*)d_in[5];
    const float* Wih1  = (const float*)d_in[6];
    const float* Whh1  = (const float*)d_in[7];
    const float* b_ih1 = (const float*)d_in[8];
    const float* b_hh1 = (const float*)d_in[9];
    const float* W1    = (const float*)d_in[10];
    const float* b1    = (const float*)d_in[11];
    const float* W2    = (const float*)d_in[12];
    const float* b2    = (const float*)d_in[13];

    char* ws = (char*)d_ws;
    size_t off = 0;
    auto take = [&](size_t bytes) { char* p = ws + off; off += (bytes + 255) & ~(size_t)255; return p; };
    float* base    = (float*)take(512 * 512 * 4);
    f16* Whh0h     = (f16*)take(HSZ * 2);
    f16* Wih1h     = (f16*)take(HSZ * 2);
    f16* Whh1h     = (f16*)take(HSZ * 2);
    f16* W1h       = (f16*)take(1048576 * 2);
    f16* W2h       = (f16*)take(524288 * 2);
    f16* h0buf     = (f16*)take(2 * HSZ * 2);
    f16* h1all     = (f16*)take((size_t)129 * HSZ * 2);
    float* pcontrib= (float*)take(128 * 512 * 4);
    f16* A         = (f16*)take(65536 * 2);
    f16* B1        = (f16*)take(65536 * 2);
    float* biasv   = (float*)take(512 * 4);
    int* slots     = (int*)take(32768 * 4);
    int* xcdtab    = (int*)take(4096 * 4);
    if (off > ws_size) return;

    // Optional monotonic h0 slabs (66 MB): enables cached/virgin h0 reads.
    const size_t h0all_bytes = (size_t)129 * HSZ * 2;
    bool big = (off + h0all_bytes + 256 <= ws_size);
    f16* h0all = big ? (f16*)take(h0all_bytes) : h0buf;

    k_conv<<<256, 256, 0, stream>>>(x, mask, Wih0, b_ih0, b_hh0, Whh0, Wih1, Whh1,
                                    W1, W2, A, B1, biasv, Whh0h, Wih1h, Whh1h,
                                    W1h, W2h, h1all, slots, xcdtab);
    k_base<<<256, 256, 0, stream>>>(A, B1, biasv, base, h0all);
    if (big)
        k_rnn<true><<<256, 256, 0, stream>>>(h0all, h1all, Whh0h, Wih1h, Whh1h,
                                             base, x, Wih0, b_ih1, b_hh1, slots,
                                             xcdtab);
    else
        k_rnn<false><<<256, 256, 0, stream>>>(h0all, h1all, Whh0h, Wih1h, Whh1h,
                                              base, x, Wih0, b_ih1, b_hh1, slots,
                                              xcdtab);
    k_phaseB<<<512, 512, 0, stream>>>(h1all, W1h, W2h, b1, b2, x, pcontrib);
    k_fin<<<512, 256, 0, stream>>>(h1all + (size_t)128 * HSZ, pcontrib, (float*)d_out);
}